// Round 1
// baseline (418.778 us; speedup 1.0000x reference)
//
#include <hip/hip_runtime.h>
#include <math.h>

#define B 64
#define H 512
#define V 50257
#define M 200
#define H2 1024
#define H3 1536
#define H4 2048

__device__ __forceinline__ float sigf(float x) { return 1.f / (1.f + expf(-x)); }

// ---------------- K1: x = relu(emb[ids]); xc = concat(x, ctx) ----------------
__global__ __launch_bounds__(256) void k_embed_concat(
    const float* __restrict__ emb, const float* __restrict__ ctx,
    const int* __restrict__ ids, float* __restrict__ xc) {
  int idx = blockIdx.x * 256 + threadIdx.x;   // B*2H
  int b = idx >> 10;
  int j = idx & 1023;
  float v;
  if (j < H) {
    v = emb[(size_t)ids[b] * H + j];
    v = v > 0.f ? v : 0.f;
  } else {
    v = ctx[b * H + (j - H)];
  }
  xc[idx] = v;
}

// ---------------- K2: LSTM gates = xc@Wih^T + bih + h0@Whh^T + bhh ----------------
__global__ __launch_bounds__(256) void k_lstm_gates(
    const float* __restrict__ xc, const float* __restrict__ h0,
    const float* __restrict__ W_ih, const float* __restrict__ W_hh,
    const float* __restrict__ b_ih, const float* __restrict__ b_hh,
    float* __restrict__ gates) {
  __shared__ float wih[4][H2];
  __shared__ float whh[4][H];
  int j0 = blockIdx.x * 4;
  int tid = threadIdx.x;
  {
    const float4* s1 = (const float4*)(W_ih + (size_t)j0 * H2);
    float4* d1 = (float4*)&wih[0][0];
    for (int i = tid; i < 1024; i += 256) d1[i] = s1[i];
    const float4* s2 = (const float4*)(W_hh + (size_t)j0 * H);
    float4* d2 = (float4*)&whh[0][0];
    for (int i = tid; i < 512; i += 256) d2[i] = s2[i];
  }
  __syncthreads();
  int b = tid & 63, jj = tid >> 6, j = j0 + jj;
  const float4* av = (const float4*)(xc + b * H2);
  const float4* wv = (const float4*)&wih[jj][0];
  float acc0 = 0.f, acc1 = 0.f;
  for (int k = 0; k < 256; k += 2) {
    float4 a = av[k], w = wv[k];
    acc0 += a.x * w.x + a.y * w.y + a.z * w.z + a.w * w.w;
    float4 a2 = av[k + 1], w2 = wv[k + 1];
    acc1 += a2.x * w2.x + a2.y * w2.y + a2.z * w2.z + a2.w * w2.w;
  }
  const float4* hv = (const float4*)(h0 + b * H);
  const float4* wv2 = (const float4*)&whh[jj][0];
  for (int k = 0; k < 128; k += 2) {
    float4 a = hv[k], w = wv2[k];
    acc0 += a.x * w.x + a.y * w.y + a.z * w.z + a.w * w.w;
    float4 a2 = hv[k + 1], w2 = wv2[k + 1];
    acc1 += a2.x * w2.x + a2.y * w2.y + a2.z * w2.z + a2.w * w2.w;
  }
  gates[b * H4 + j] = acc0 + acc1 + b_ih[j] + b_hh[j];
}

// ---------------- K3: LSTM cell elementwise ----------------
__global__ __launch_bounds__(256) void k_lstm_cell(
    const float* __restrict__ gates, const float* __restrict__ c0,
    float* __restrict__ h1, float* __restrict__ c1) {
  int idx = blockIdx.x * 256 + threadIdx.x;  // B*H
  int b = idx >> 9, h = idx & 511;
  const float* g = gates + b * H4;
  float gi = g[h], gf = g[H + h], gg = g[2 * H + h], go = g[3 * H + h];
  float c = sigf(gf) * c0[idx] + sigf(gi) * tanhf(gg);
  c1[idx] = c;
  h1[idx] = sigf(go) * tanhf(c);
}

// ---------------- K4: attn[b][m] = m_emb[mt[m][b]] . h1[b] ----------------
__global__ __launch_bounds__(256) void k_attn_scores(
    const float* __restrict__ m_emb, const int* __restrict__ mt,
    const float* __restrict__ h1, float* __restrict__ attn) {
  int wave = (blockIdx.x * 256 + threadIdx.x) >> 6;
  int lane = threadIdx.x & 63;
  int m = wave >> 6, b = wave & 63;
  int row = mt[m * B + b];
  const float4* e = (const float4*)(m_emb + (size_t)row * H);
  const float4* hv = (const float4*)(h1 + b * H);
  float4 a0 = e[lane], a1 = e[64 + lane];
  float4 b0 = hv[lane], b1 = hv[64 + lane];
  float acc = a0.x * b0.x + a0.y * b0.y + a0.z * b0.z + a0.w * b0.w +
              a1.x * b1.x + a1.y * b1.y + a1.z * b1.z + a1.w * b1.w;
  for (int off = 32; off > 0; off >>= 1) acc += __shfl_down(acc, off);
  if (lane == 0) attn[b * M + m] = acc;
}

// ---------------- K5: attn2 = attn @ attn_W^T + attn_b; log_softmax ----------------
__global__ __launch_bounds__(256) void k_attn_lin_lsm(
    const float* __restrict__ attn, const float* __restrict__ attn_W,
    const float* __restrict__ attn_b, float* __restrict__ attn_d) {
  __shared__ float arow[M];
  __shared__ float vals[256];
  __shared__ float red[256];
  int b = blockIdx.x, tid = threadIdx.x;
  if (tid < M) arow[tid] = attn[b * M + tid];
  __syncthreads();
  float v = -1e30f;
  if (tid < M) {
    const float* w = attn_W + tid * M;
    float a0 = attn_b[tid], a1 = 0.f;
    for (int m = 0; m < M; m += 2) {
      a0 = fmaf(arow[m], w[m], a0);
      a1 = fmaf(arow[m + 1], w[m + 1], a1);
    }
    v = a0 + a1;
  }
  vals[tid] = v;
  red[tid] = v;
  __syncthreads();
  for (int off = 128; off > 0; off >>= 1) {
    if (tid < off) red[tid] = fmaxf(red[tid], red[tid + off]);
    __syncthreads();
  }
  float mx = red[0];
  __syncthreads();
  red[tid] = (tid < M) ? expf(vals[tid] - mx) : 0.f;
  __syncthreads();
  for (int off = 128; off > 0; off >>= 1) {
    if (tid < off) red[tid] += red[tid + off];
    __syncthreads();
  }
  float lse = mx + logf(red[0]);
  if (tid < M) attn_d[b * M + tid] = vals[tid] - lse;
}

// ---------------- K6: memory_context partial sums over m-chunks ----------------
__global__ __launch_bounds__(256) void k_mem_ctx_partial(
    const float* __restrict__ c_emb, const int* __restrict__ mt,
    const float* __restrict__ attn_d, float* __restrict__ mcp) {
  int b = blockIdx.x;     // 64
  int chunk = blockIdx.y; // 8
  int tid = threadIdx.x;  // 256
  __shared__ int rows[25];
  __shared__ float w[25];
  if (tid < 25) {
    int m = chunk * 25 + tid;
    rows[tid] = mt[m * B + b];
    w[tid] = attn_d[b * M + m];
  }
  __syncthreads();
  float acc0 = 0.f, acc1 = 0.f;
  #pragma unroll 5
  for (int i = 0; i < 25; ++i) {
    const float* e = c_emb + (size_t)rows[i] * H;
    acc0 = fmaf(w[i], e[tid], acc0);
    acc1 = fmaf(w[i], e[256 + tid], acc1);
  }
  mcp[(chunk * B + b) * H + tid] = acc0;
  mcp[(chunk * B + b) * H + 256 + tid] = acc1;
}

__global__ __launch_bounds__(256) void k_mem_ctx_reduce(
    const float* __restrict__ mcp, float* __restrict__ mc) {
  int idx = blockIdx.x * 256 + threadIdx.x;  // B*H
  float s = 0.f;
  for (int c = 0; c < 8; ++c) s += mcp[c * (B * H) + idx];
  mc[idx] = s;
}

// ---------------- K7: GRU gates (two H->3H GEMMs) ----------------
__global__ __launch_bounds__(256) void k_gru_gates(
    const float* __restrict__ mc, const float* __restrict__ h1,
    const float* __restrict__ W_ih, const float* __restrict__ W_hh,
    const float* __restrict__ b_ih, const float* __restrict__ b_hh,
    float* __restrict__ gi, float* __restrict__ gh) {
  __shared__ float wis[4][H];
  __shared__ float whs[4][H];
  int j0 = blockIdx.x * 4;
  int tid = threadIdx.x;
  {
    const float4* s1 = (const float4*)(W_ih + (size_t)j0 * H);
    float4* d1 = (float4*)&wis[0][0];
    for (int i = tid; i < 512; i += 256) d1[i] = s1[i];
    const float4* s2 = (const float4*)(W_hh + (size_t)j0 * H);
    float4* d2 = (float4*)&whs[0][0];
    for (int i = tid; i < 512; i += 256) d2[i] = s2[i];
  }
  __syncthreads();
  int b = tid & 63, jj = tid >> 6, j = j0 + jj;
  {
    const float4* a = (const float4*)(mc + b * H);
    const float4* w = (const float4*)&wis[jj][0];
    float acc0 = 0.f, acc1 = 0.f;
    for (int k = 0; k < 128; k += 2) {
      float4 x = a[k], y = w[k];
      acc0 += x.x * y.x + x.y * y.y + x.z * y.z + x.w * y.w;
      float4 x2 = a[k + 1], y2 = w[k + 1];
      acc1 += x2.x * y2.x + x2.y * y2.y + x2.z * y2.z + x2.w * y2.w;
    }
    gi[b * H3 + j] = acc0 + acc1 + b_ih[j];
  }
  {
    const float4* a = (const float4*)(h1 + b * H);
    const float4* w = (const float4*)&whs[jj][0];
    float acc0 = 0.f, acc1 = 0.f;
    for (int k = 0; k < 128; k += 2) {
      float4 x = a[k], y = w[k];
      acc0 += x.x * y.x + x.y * y.y + x.z * y.z + x.w * y.w;
      float4 x2 = a[k + 1], y2 = w[k + 1];
      acc1 += x2.x * y2.x + x2.y * y2.y + x2.z * y2.z + x2.w * y2.w;
    }
    gh[b * H3 + j] = acc0 + acc1 + b_hh[j];
  }
}

// ---------------- K8: GRU combine + build mbc = [mb, ctx] ----------------
__global__ __launch_bounds__(256) void k_gru_combine(
    const float* __restrict__ gi, const float* __restrict__ gh,
    const float* __restrict__ h1, const float* __restrict__ ctx,
    float* __restrict__ mbc) {
  int idx = blockIdx.x * 256 + threadIdx.x;  // B*H
  int b = idx >> 9, h = idx & 511;
  const float* gib = gi + b * H3;
  const float* ghb = gh + b * H3;
  float r = sigf(gib[h] + ghb[h]);
  float z = sigf(gib[H + h] + ghb[H + h]);
  float n = tanhf(gib[2 * H + h] + r * ghb[2 * H + h]);
  float mb = (1.f - z) * n + z * h1[idx];
  mbc[b * H2 + h] = mb;
  mbc[b * H2 + H + h] = ctx[idx];
}

// ---------------- K9: logits = mbc @ out_W^T + out_b (fp32 tiled) ----------------
__global__ __launch_bounds__(256) void k_out_gemm(
    const float* __restrict__ A, const float* __restrict__ W,
    const float* __restrict__ bias, float* __restrict__ out) {
  __shared__ float As[32][68];
  __shared__ float Bs[32][68];
  const int tid = threadIdx.x;
  const int v0 = blockIdx.x * 64;
  const int tx = tid & 15;
  const int ty = tid >> 4;
  float acc[4][4];
  #pragma unroll
  for (int i = 0; i < 4; ++i)
    #pragma unroll
    for (int j = 0; j < 4; ++j) acc[i][j] = 0.f;

  for (int k0 = 0; k0 < H2; k0 += 32) {
    #pragma unroll
    for (int i = 0; i < 2; ++i) {
      int vid = tid + i * 256;
      int r = vid >> 3;
      int kk = (vid & 7) << 2;
      float4 x = *(const float4*)(A + r * H2 + k0 + kk);
      As[kk + 0][r] = x.x; As[kk + 1][r] = x.y;
      As[kk + 2][r] = x.z; As[kk + 3][r] = x.w;
      int vr = v0 + r;
      float4 y = make_float4(0.f, 0.f, 0.f, 0.f);
      if (vr < V) y = *(const float4*)(W + (size_t)vr * H2 + k0 + kk);
      Bs[kk + 0][r] = y.x; Bs[kk + 1][r] = y.y;
      Bs[kk + 2][r] = y.z; Bs[kk + 3][r] = y.w;
    }
    __syncthreads();
    #pragma unroll 8
    for (int k = 0; k < 32; ++k) {
      float4 av = *(const float4*)&As[k][ty * 4];
      float w0 = Bs[k][tx], w1 = Bs[k][16 + tx];
      float w2 = Bs[k][32 + tx], w3 = Bs[k][48 + tx];
      acc[0][0] = fmaf(av.x, w0, acc[0][0]);
      acc[0][1] = fmaf(av.x, w1, acc[0][1]);
      acc[0][2] = fmaf(av.x, w2, acc[0][2]);
      acc[0][3] = fmaf(av.x, w3, acc[0][3]);
      acc[1][0] = fmaf(av.y, w0, acc[1][0]);
      acc[1][1] = fmaf(av.y, w1, acc[1][1]);
      acc[1][2] = fmaf(av.y, w2, acc[1][2]);
      acc[1][3] = fmaf(av.y, w3, acc[1][3]);
      acc[2][0] = fmaf(av.z, w0, acc[2][0]);
      acc[2][1] = fmaf(av.z, w1, acc[2][1]);
      acc[2][2] = fmaf(av.z, w2, acc[2][2]);
      acc[2][3] = fmaf(av.z, w3, acc[2][3]);
      acc[3][0] = fmaf(av.w, w0, acc[3][0]);
      acc[3][1] = fmaf(av.w, w1, acc[3][1]);
      acc[3][2] = fmaf(av.w, w2, acc[3][2]);
      acc[3][3] = fmaf(av.w, w3, acc[3][3]);
    }
    __syncthreads();
  }
  #pragma unroll
  for (int j = 0; j < 4; ++j) {
    int v = v0 + j * 16 + tx;
    if (v < V) {
      float bv = bias[v];
      #pragma unroll
      for (int i = 0; i < 4; ++i) {
        int b = ty * 4 + i;
        out[(size_t)b * V + v] = acc[i][j] + bv;
      }
    }
  }
}

// ---------------- K10: per-row logsumexp over V ----------------
__global__ __launch_bounds__(256) void k_lsm_reduce(
    const float* __restrict__ logits, float* __restrict__ red) {
  int b = blockIdx.x, tid = threadIdx.x;
  const float* row = logits + (size_t)b * V;
  float m = -1e30f, s = 0.f;
  for (int v = tid; v < V; v += 256) {
    float x = row[v];
    if (x <= m) {
      s += expf(x - m);
    } else {
      s = s * expf(m - x) + 1.f;
      m = x;
    }
  }
  __shared__ float sm[256], ss[256];
  sm[tid] = m; ss[tid] = s;
  __syncthreads();
  for (int off = 128; off > 0; off >>= 1) {
    if (tid < off) {
      float m1 = sm[tid], s1 = ss[tid];
      float m2 = sm[tid + off], s2 = ss[tid + off];
      float nm = fmaxf(m1, m2);
      sm[tid] = nm;
      ss[tid] = s1 * expf(m1 - nm) + s2 * expf(m2 - nm);
    }
    __syncthreads();
  }
  if (tid == 0) red[b] = sm[0] + logf(ss[0]);
}

// ---------------- K11: out = logits - lse[b] (in place) ----------------
__global__ __launch_bounds__(256) void k_lsm_apply(
    float* __restrict__ out, const float* __restrict__ red) {
  int v = blockIdx.x * 256 + threadIdx.x;
  int b = blockIdx.y;
  if (v < V) out[(size_t)b * V + v] -= red[b];
}

extern "C" void kernel_launch(void* const* d_in, const int* in_sizes, int n_in,
                              void* d_out, int out_size, void* d_ws, size_t ws_size,
                              hipStream_t stream) {
  const float* h0    = (const float*)d_in[0];
  const float* c0    = (const float*)d_in[1];
  const float* ctx   = (const float*)d_in[2];
  const float* emb   = (const float*)d_in[3];
  const float* m_emb = (const float*)d_in[4];
  const float* c_emb = (const float*)d_in[5];
  const float* lWih  = (const float*)d_in[6];
  const float* lWhh  = (const float*)d_in[7];
  const float* lbih  = (const float*)d_in[8];
  const float* lbhh  = (const float*)d_in[9];
  const float* gWih  = (const float*)d_in[10];
  const float* gWhh  = (const float*)d_in[11];
  const float* gbih  = (const float*)d_in[12];
  const float* gbhh  = (const float*)d_in[13];
  const float* aW    = (const float*)d_in[14];
  const float* ab    = (const float*)d_in[15];
  const float* oW    = (const float*)d_in[16];
  const float* ob    = (const float*)d_in[17];
  const int* ids     = (const int*)d_in[18];
  const int* mt      = (const int*)d_in[19];

  float* out = (float*)d_out;
  float* h1  = out + (size_t)B * V;
  float* c1  = h1 + B * H;

  float* ws    = (float*)d_ws;
  float* xc    = ws;               // B*H2   = 65536
  float* gates = xc + B * H2;      // B*H4   = 131072
  float* attn  = gates + B * H4;   // B*M    = 12800
  float* attnd = attn + B * M;     // B*M    = 12800
  float* mc    = attnd + B * M;    // B*H    = 32768
  float* gi    = mc + B * H;       // B*H3   = 98304
  float* gh    = gi + B * H3;      // B*H3   = 98304
  float* mbc   = gh + B * H3;      // B*H2   = 65536
  float* red   = mbc + B * H2;     // 256
  float* mcp   = red + 256;        // 8*B*H  = 262144

  k_embed_concat<<<(B * H2) / 256, 256, 0, stream>>>(emb, ctx, ids, xc);
  k_lstm_gates<<<H4 / 4, 256, 0, stream>>>(xc, h0, lWih, lWhh, lbih, lbhh, gates);
  k_lstm_cell<<<(B * H) / 256, 256, 0, stream>>>(gates, c0, h1, c1);
  k_attn_scores<<<(M * B) / 4, 256, 0, stream>>>(m_emb, mt, h1, attn);
  k_attn_lin_lsm<<<B, 256, 0, stream>>>(attn, aW, ab, attnd);
  dim3 g6(B, 8);
  k_mem_ctx_partial<<<g6, 256, 0, stream>>>(c_emb, mt, attnd, mcp);
  k_mem_ctx_reduce<<<(B * H) / 256, 256, 0, stream>>>(mcp, mc);
  k_gru_gates<<<H3 / 4, 256, 0, stream>>>(mc, h1, gWih, gWhh, gbih, gbhh, gi, gh);
  k_gru_combine<<<(B * H) / 256, 256, 0, stream>>>(gi, gh, h1, ctx, mbc);
  k_out_gemm<<<(V + 63) / 64, 256, 0, stream>>>(mbc, oW, ob, out);
  k_lsm_reduce<<<B, 256, 0, stream>>>(out, red);
  dim3 g11((V + 255) / 256, B);
  k_lsm_apply<<<g11, 256, 0, stream>>>(out, red);
}

// Round 2
// 291.223 us; speedup vs baseline: 1.4380x; 1.4380x over previous
//
#include <hip/hip_runtime.h>
#include <math.h>

#define B 64
#define H 512
#define V 50257
#define M 200
#define H2 1024
#define H3 1536
#define H4 2048

typedef short short8 __attribute__((ext_vector_type(8)));
typedef float f32x4 __attribute__((ext_vector_type(4)));

__device__ __forceinline__ float sigf(float x) { return 1.f / (1.f + expf(-x)); }

// f32 -> bf16 (RNE) as raw short
__device__ __forceinline__ short bf16c(float f) {
  unsigned u = __builtin_bit_cast(unsigned, f);
  unsigned r = u + 0x7fffu + ((u >> 16) & 1u);
  return (short)(r >> 16);
}

// ---------------- K1: x = relu(emb[ids]); xc = concat(x, ctx) ----------------
__global__ __launch_bounds__(256) void k_embed_concat(
    const float* __restrict__ emb, const float* __restrict__ ctx,
    const int* __restrict__ ids, float* __restrict__ xc) {
  int idx = blockIdx.x * 256 + threadIdx.x;   // B*2H
  int b = idx >> 10;
  int j = idx & 1023;
  float v;
  if (j < H) {
    v = emb[(size_t)ids[b] * H + j];
    v = v > 0.f ? v : 0.f;
  } else {
    v = ctx[b * H + (j - H)];
  }
  xc[idx] = v;
}

// ---------------- K2: LSTM gates ----------------
__global__ __launch_bounds__(256) void k_lstm_gates(
    const float* __restrict__ xc, const float* __restrict__ h0,
    const float* __restrict__ W_ih, const float* __restrict__ W_hh,
    const float* __restrict__ b_ih, const float* __restrict__ b_hh,
    float* __restrict__ gates) {
  __shared__ float wih[4][H2];
  __shared__ float whh[4][H];
  int j0 = blockIdx.x * 4;
  int tid = threadIdx.x;
  {
    const float4* s1 = (const float4*)(W_ih + (size_t)j0 * H2);
    float4* d1 = (float4*)&wih[0][0];
    for (int i = tid; i < 1024; i += 256) d1[i] = s1[i];
    const float4* s2 = (const float4*)(W_hh + (size_t)j0 * H);
    float4* d2 = (float4*)&whh[0][0];
    for (int i = tid; i < 512; i += 256) d2[i] = s2[i];
  }
  __syncthreads();
  int b = tid & 63, jj = tid >> 6, j = j0 + jj;
  const float4* av = (const float4*)(xc + b * H2);
  const float4* wv = (const float4*)&wih[jj][0];
  float acc0 = 0.f, acc1 = 0.f;
  for (int k = 0; k < 256; k += 2) {
    float4 a = av[k], w = wv[k];
    acc0 += a.x * w.x + a.y * w.y + a.z * w.z + a.w * w.w;
    float4 a2 = av[k + 1], w2 = wv[k + 1];
    acc1 += a2.x * w2.x + a2.y * w2.y + a2.z * w2.z + a2.w * w2.w;
  }
  const float4* hv = (const float4*)(h0 + b * H);
  const float4* wv2 = (const float4*)&whh[jj][0];
  for (int k = 0; k < 128; k += 2) {
    float4 a = hv[k], w = wv2[k];
    acc0 += a.x * w.x + a.y * w.y + a.z * w.z + a.w * w.w;
    float4 a2 = hv[k + 1], w2 = wv2[k + 1];
    acc1 += a2.x * w2.x + a2.y * w2.y + a2.z * w2.z + a2.w * w2.w;
  }
  gates[b * H4 + j] = acc0 + acc1 + b_ih[j] + b_hh[j];
}

// ---------------- K3: LSTM cell elementwise ----------------
__global__ __launch_bounds__(256) void k_lstm_cell(
    const float* __restrict__ gates, const float* __restrict__ c0,
    float* __restrict__ h1, float* __restrict__ c1) {
  int idx = blockIdx.x * 256 + threadIdx.x;  // B*H
  int b = idx >> 9, h = idx & 511;
  const float* g = gates + b * H4;
  float gi = g[h], gf = g[H + h], gg = g[2 * H + h], go = g[3 * H + h];
  float c = sigf(gf) * c0[idx] + sigf(gi) * tanhf(gg);
  c1[idx] = c;
  h1[idx] = sigf(go) * tanhf(c);
}

// ---------------- K4: attn[b][m] = m_emb[mt[m][b]] . h1[b] ----------------
__global__ __launch_bounds__(256) void k_attn_scores(
    const float* __restrict__ m_emb, const int* __restrict__ mt,
    const float* __restrict__ h1, float* __restrict__ attn) {
  int wave = (blockIdx.x * 256 + threadIdx.x) >> 6;
  int lane = threadIdx.x & 63;
  int m = wave >> 6, b = wave & 63;
  int row = mt[m * B + b];
  const float4* e = (const float4*)(m_emb + (size_t)row * H);
  const float4* hv = (const float4*)(h1 + b * H);
  float4 a0 = e[lane], a1 = e[64 + lane];
  float4 b0 = hv[lane], b1 = hv[64 + lane];
  float acc = a0.x * b0.x + a0.y * b0.y + a0.z * b0.z + a0.w * b0.w +
              a1.x * b1.x + a1.y * b1.y + a1.z * b1.z + a1.w * b1.w;
  for (int off = 32; off > 0; off >>= 1) acc += __shfl_down(acc, off);
  if (lane == 0) attn[b * M + m] = acc;
}

// ---------------- K5: attn2 = attn @ attn_W^T + attn_b; log_softmax ----------------
__global__ __launch_bounds__(256) void k_attn_lin_lsm(
    const float* __restrict__ attn, const float* __restrict__ attn_W,
    const float* __restrict__ attn_b, float* __restrict__ attn_d) {
  __shared__ float arow[M];
  __shared__ float vals[256];
  __shared__ float red[256];
  int b = blockIdx.x, tid = threadIdx.x;
  if (tid < M) arow[tid] = attn[b * M + tid];
  __syncthreads();
  float v = -1e30f;
  if (tid < M) {
    const float* w = attn_W + tid * M;
    float a0 = attn_b[tid], a1 = 0.f;
    for (int m = 0; m < M; m += 2) {
      a0 = fmaf(arow[m], w[m], a0);
      a1 = fmaf(arow[m + 1], w[m + 1], a1);
    }
    v = a0 + a1;
  }
  vals[tid] = v;
  red[tid] = v;
  __syncthreads();
  for (int off = 128; off > 0; off >>= 1) {
    if (tid < off) red[tid] = fmaxf(red[tid], red[tid + off]);
    __syncthreads();
  }
  float mx = red[0];
  __syncthreads();
  red[tid] = (tid < M) ? expf(vals[tid] - mx) : 0.f;
  __syncthreads();
  for (int off = 128; off > 0; off >>= 1) {
    if (tid < off) red[tid] += red[tid + off];
    __syncthreads();
  }
  float lse = mx + logf(red[0]);
  if (tid < M) attn_d[b * M + tid] = vals[tid] - lse;
}

// ---------------- K6: memory_context partial sums over m-chunks ----------------
__global__ __launch_bounds__(256) void k_mem_ctx_partial(
    const float* __restrict__ c_emb, const int* __restrict__ mt,
    const float* __restrict__ attn_d, float* __restrict__ mcp) {
  int b = blockIdx.x;     // 64
  int chunk = blockIdx.y; // 8
  int tid = threadIdx.x;  // 256
  __shared__ int rows[25];
  __shared__ float w[25];
  if (tid < 25) {
    int m = chunk * 25 + tid;
    rows[tid] = mt[m * B + b];
    w[tid] = attn_d[b * M + m];
  }
  __syncthreads();
  float acc0 = 0.f, acc1 = 0.f;
  #pragma unroll 5
  for (int i = 0; i < 25; ++i) {
    const float* e = c_emb + (size_t)rows[i] * H;
    acc0 = fmaf(w[i], e[tid], acc0);
    acc1 = fmaf(w[i], e[256 + tid], acc1);
  }
  mcp[(chunk * B + b) * H + tid] = acc0;
  mcp[(chunk * B + b) * H + 256 + tid] = acc1;
}

__global__ __launch_bounds__(256) void k_mem_ctx_reduce(
    const float* __restrict__ mcp, float* __restrict__ mc) {
  int idx = blockIdx.x * 256 + threadIdx.x;  // B*H
  float s = 0.f;
  for (int c = 0; c < 8; ++c) s += mcp[c * (B * H) + idx];
  mc[idx] = s;
}

// ---------------- K7: GRU gates ----------------
__global__ __launch_bounds__(256) void k_gru_gates(
    const float* __restrict__ mc, const float* __restrict__ h1,
    const float* __restrict__ W_ih, const float* __restrict__ W_hh,
    const float* __restrict__ b_ih, const float* __restrict__ b_hh,
    float* __restrict__ gi, float* __restrict__ gh) {
  __shared__ float wis[4][H];
  __shared__ float whs[4][H];
  int j0 = blockIdx.x * 4;
  int tid = threadIdx.x;
  {
    const float4* s1 = (const float4*)(W_ih + (size_t)j0 * H);
    float4* d1 = (float4*)&wis[0][0];
    for (int i = tid; i < 512; i += 256) d1[i] = s1[i];
    const float4* s2 = (const float4*)(W_hh + (size_t)j0 * H);
    float4* d2 = (float4*)&whs[0][0];
    for (int i = tid; i < 512; i += 256) d2[i] = s2[i];
  }
  __syncthreads();
  int b = tid & 63, jj = tid >> 6, j = j0 + jj;
  {
    const float4* a = (const float4*)(mc + b * H);
    const float4* w = (const float4*)&wis[jj][0];
    float acc0 = 0.f, acc1 = 0.f;
    for (int k = 0; k < 128; k += 2) {
      float4 x = a[k], y = w[k];
      acc0 += x.x * y.x + x.y * y.y + x.z * y.z + x.w * y.w;
      float4 x2 = a[k + 1], y2 = w[k + 1];
      acc1 += x2.x * y2.x + x2.y * y2.y + x2.z * y2.z + x2.w * y2.w;
    }
    gi[b * H3 + j] = acc0 + acc1 + b_ih[j];
  }
  {
    const float4* a = (const float4*)(h1 + b * H);
    const float4* w = (const float4*)&whs[jj][0];
    float acc0 = 0.f, acc1 = 0.f;
    for (int k = 0; k < 128; k += 2) {
      float4 x = a[k], y = w[k];
      acc0 += x.x * y.x + x.y * y.y + x.z * y.z + x.w * y.w;
      float4 x2 = a[k + 1], y2 = w[k + 1];
      acc1 += x2.x * y2.x + x2.y * y2.y + x2.z * y2.z + x2.w * y2.w;
    }
    gh[b * H3 + j] = acc0 + acc1 + b_hh[j];
  }
}

// ---------------- K8: GRU combine + build A (bf16) = [mb, ctx] ----------------
__global__ __launch_bounds__(256) void k_gru_combine(
    const float* __restrict__ gi, const float* __restrict__ gh,
    const float* __restrict__ h1, const float* __restrict__ ctx,
    short* __restrict__ Abf) {
  int idx = blockIdx.x * 256 + threadIdx.x;  // B*H
  int b = idx >> 9, h = idx & 511;
  const float* gib = gi + b * H3;
  const float* ghb = gh + b * H3;
  float r = sigf(gib[h] + ghb[h]);
  float z = sigf(gib[H + h] + ghb[H + h]);
  float n = tanhf(gib[2 * H + h] + r * ghb[2 * H + h]);
  float mb = (1.f - z) * n + z * h1[idx];
  Abf[b * H2 + h] = bf16c(mb);
  Abf[b * H2 + H + h] = bf16c(ctx[idx]);
}

// ---------------- K9: logits = A @ W^T + bias via bf16 MFMA ----------------
// A: bf16 [64][1024]. W: f32 [V][1024] (converted to bf16 in-register).
// Per block: 4 waves, each wave owns 2 v-tiles of 16 cols -> 128 v per block.
// Per wave: acc[4 m-tiles][2 v-tiles] of f32x4. No LDS, no barriers.
__global__ __launch_bounds__(256) void k_out_gemm_mfma(
    const short* __restrict__ Abf, const float* __restrict__ W,
    const float* __restrict__ bias, float* __restrict__ out) {
  const int tid = threadIdx.x;
  const int lane = tid & 63;
  const int wid = tid >> 6;
  const int col = lane & 15;      // v within tile / A row within tile
  const int g = lane >> 4;        // k-window (8 elems each)

  const int v_t0 = blockIdx.x * 128 + wid * 32;
  const int v0 = v_t0 + col;
  const int v1 = v_t0 + 16 + col;
  const int v0c = v0 < V ? v0 : V - 1;
  const int v1c = v1 < V ? v1 : V - 1;

  const float* w0p = W + (size_t)v0c * H2 + g * 8;
  const float* w1p = W + (size_t)v1c * H2 + g * 8;
  const short* ap = Abf + col * H2 + g * 8;

  f32x4 acc[4][2];
  #pragma unroll
  for (int t = 0; t < 4; ++t) {
    acc[t][0] = (f32x4)(0.f);
    acc[t][1] = (f32x4)(0.f);
  }

  #pragma unroll 2
  for (int k0 = 0; k0 < H2; k0 += 32) {
    float4 wa0 = *(const float4*)(w0p + k0);
    float4 wb0 = *(const float4*)(w0p + k0 + 4);
    float4 wa1 = *(const float4*)(w1p + k0);
    float4 wb1 = *(const float4*)(w1p + k0 + 4);
    short8 bf0, bf1;
    bf0[0] = bf16c(wa0.x); bf0[1] = bf16c(wa0.y);
    bf0[2] = bf16c(wa0.z); bf0[3] = bf16c(wa0.w);
    bf0[4] = bf16c(wb0.x); bf0[5] = bf16c(wb0.y);
    bf0[6] = bf16c(wb0.z); bf0[7] = bf16c(wb0.w);
    bf1[0] = bf16c(wa1.x); bf1[1] = bf16c(wa1.y);
    bf1[2] = bf16c(wa1.z); bf1[3] = bf16c(wa1.w);
    bf1[4] = bf16c(wb1.x); bf1[5] = bf16c(wb1.y);
    bf1[6] = bf16c(wb1.z); bf1[7] = bf16c(wb1.w);
    #pragma unroll
    for (int t = 0; t < 4; ++t) {
      short8 af = *(const short8*)(ap + t * 16 * H2 + k0);
      acc[t][0] = __builtin_amdgcn_mfma_f32_16x16x32_bf16(af, bf0, acc[t][0], 0, 0, 0);
      acc[t][1] = __builtin_amdgcn_mfma_f32_16x16x32_bf16(af, bf1, acc[t][1], 0, 0, 0);
    }
  }

  // Epilogue: D lane mapping: col = lane&15, row = (lane>>4)*4 + r
  #pragma unroll
  for (int u = 0; u < 2; ++u) {
    int v = v_t0 + u * 16 + col;
    if (v < V) {
      float bv = bias[v];
      #pragma unroll
      for (int t = 0; t < 4; ++t) {
        #pragma unroll
        for (int r = 0; r < 4; ++r) {
          int b = t * 16 + g * 4 + r;
          out[(size_t)b * V + v] = acc[t][u][r] + bv;
        }
      }
    }
  }
}

// ---------------- K10: split-V partial logsumexp. grid (16, B) ----------------
#define LSM_CS 3152
__global__ __launch_bounds__(256) void k_lsm_partial(
    const float* __restrict__ logits, float* __restrict__ pm, float* __restrict__ ps) {
  int chunk = blockIdx.x, b = blockIdx.y, tid = threadIdx.x;
  int start = chunk * LSM_CS;
  int end = start + LSM_CS < V ? start + LSM_CS : V;
  const float* row = logits + (size_t)b * V;
  float m = -1e30f, s = 0.f;
  for (int v = start + tid * 4; v < end; v += 1024) {
    float x4[4];
    int nv = end - v < 4 ? end - v : 4;
    if (nv == 4) {
      float4 x = *(const float4*)(row + v);
      x4[0] = x.x; x4[1] = x.y; x4[2] = x.z; x4[3] = x.w;
    } else {
      for (int i = 0; i < nv; ++i) x4[i] = row[v + i];
    }
    for (int i = 0; i < nv; ++i) {
      float x = x4[i];
      if (x <= m) {
        s += expf(x - m);
      } else {
        s = s * expf(m - x) + 1.f;
        m = x;
      }
    }
  }
  __shared__ float sm[256], ss[256];
  sm[tid] = m; ss[tid] = s;
  __syncthreads();
  for (int off = 128; off > 0; off >>= 1) {
    if (tid < off) {
      float m1 = sm[tid], s1 = ss[tid];
      float m2 = sm[tid + off], s2 = ss[tid + off];
      float nm = fmaxf(m1, m2);
      sm[tid] = nm;
      ss[tid] = s1 * expf(m1 - nm) + s2 * expf(m2 - nm);
    }
    __syncthreads();
  }
  if (tid == 0) { pm[b * 16 + chunk] = sm[0]; ps[b * 16 + chunk] = ss[0]; }
}

// ---------------- K11: out -= lse (combine 16 partials inline). grid (50, B) ----------------
__global__ __launch_bounds__(256) void k_lsm_apply(
    float* __restrict__ out, const float* __restrict__ pm, const float* __restrict__ ps) {
  int b = blockIdx.y, tid = threadIdx.x;
  float m = -1e30f, s = 0.f;
  #pragma unroll
  for (int c = 0; c < 16; ++c) {
    float m2 = pm[b * 16 + c], s2 = ps[b * 16 + c];
    float nm = fmaxf(m, m2);
    s = s * expf(m - nm) + s2 * expf(m2 - nm);
    m = nm;
  }
  float lse = m + logf(s);
  int v = blockIdx.x * 1024 + tid * 4;
  float* row = out + (size_t)b * V;
  if (v + 3 < V) {
    float4 x = *(const float4*)(row + v);
    x.x -= lse; x.y -= lse; x.z -= lse; x.w -= lse;
    *(float4*)(row + v) = x;
  } else {
    for (int i = 0; i < 4 && v + i < V; ++i) row[v + i] -= lse;
  }
}

extern "C" void kernel_launch(void* const* d_in, const int* in_sizes, int n_in,
                              void* d_out, int out_size, void* d_ws, size_t ws_size,
                              hipStream_t stream) {
  const float* h0    = (const float*)d_in[0];
  const float* c0    = (const float*)d_in[1];
  const float* ctx   = (const float*)d_in[2];
  const float* emb   = (const float*)d_in[3];
  const float* m_emb = (const float*)d_in[4];
  const float* c_emb = (const float*)d_in[5];
  const float* lWih  = (const float*)d_in[6];
  const float* lWhh  = (const float*)d_in[7];
  const float* lbih  = (const float*)d_in[8];
  const float* lbhh  = (const float*)d_in[9];
  const float* gWih  = (const float*)d_in[10];
  const float* gWhh  = (const float*)d_in[11];
  const float* gbih  = (const float*)d_in[12];
  const float* gbhh  = (const float*)d_in[13];
  const float* aW    = (const float*)d_in[14];
  const float* ab    = (const float*)d_in[15];
  const float* oW    = (const float*)d_in[16];
  const float* ob    = (const float*)d_in[17];
  const int* ids     = (const int*)d_in[18];
  const int* mt      = (const int*)d_in[19];

  float* out = (float*)d_out;
  float* h1  = out + (size_t)B * V;
  float* c1  = h1 + B * H;

  float* ws    = (float*)d_ws;
  float* xc    = ws;               // B*H2   = 65536
  float* gates = xc + B * H2;      // B*H4   = 131072
  float* attn  = gates + B * H4;   // B*M    = 12800
  float* attnd = attn + B * M;     // B*M    = 12800
  float* mc    = attnd + B * M;    // B*H    = 32768
  float* gi    = mc + B * H;       // B*H3   = 98304
  float* gh    = gi + B * H3;      // B*H3   = 98304
  float* pm    = gh + B * H3;      // 1024
  float* ps    = pm + 1024;        // 1024
  float* mcp   = ps + 1024;        // 8*B*H  = 262144
  short* Abf   = (short*)(mcp + 8 * B * H);  // 64*1024 bf16 = 128KB

  k_embed_concat<<<(B * H2) / 256, 256, 0, stream>>>(emb, ctx, ids, xc);
  k_lstm_gates<<<H4 / 4, 256, 0, stream>>>(xc, h0, lWih, lWhh, lbih, lbhh, gates);
  k_lstm_cell<<<(B * H) / 256, 256, 0, stream>>>(gates, c0, h1, c1);
  k_attn_scores<<<(M * B) / 4, 256, 0, stream>>>(m_emb, mt, h1, attn);
  k_attn_lin_lsm<<<B, 256, 0, stream>>>(attn, aW, ab, attnd);
  dim3 g6(B, 8);
  k_mem_ctx_partial<<<g6, 256, 0, stream>>>(c_emb, mt, attnd, mcp);
  k_mem_ctx_reduce<<<(B * H) / 256, 256, 0, stream>>>(mcp, mc);
  k_gru_gates<<<H3 / 4, 256, 0, stream>>>(mc, h1, gWih, gWhh, gbih, gbhh, gi, gh);
  k_gru_combine<<<(B * H) / 256, 256, 0, stream>>>(gi, gh, h1, ctx, Abf);
  k_out_gemm_mfma<<<(V + 127) / 128, 256, 0, stream>>>(Abf, oW, ob, out);
  dim3 g10(16, B);
  k_lsm_partial<<<g10, 256, 0, stream>>>(out, pm, ps);
  dim3 g11(50, B);
  k_lsm_apply<<<g11, 256, 0, stream>>>(out, pm, ps);
}

// Round 4
// 161.392 us; speedup vs baseline: 2.5948x; 1.8044x over previous
//
#include <hip/hip_runtime.h>
#include <math.h>

#define B 64
#define H 512
#define V 50257
#define M 200
#define H2 1024
#define H3 1536
#define H4 2048
#define NB 786             // ceil(V/64) = number of out-GEMM blocks

typedef short short8 __attribute__((ext_vector_type(8)));
typedef float f32x4 __attribute__((ext_vector_type(4)));

__device__ __forceinline__ float sigf(float x) { return 1.f / (1.f + expf(-x)); }

// f32 -> bf16 (RNE) as raw short
__device__ __forceinline__ short bf16c(float f) {
  unsigned u = __builtin_bit_cast(unsigned, f);
  unsigned r = u + 0x7fffu + ((u >> 16) & 1u);
  return (short)(r >> 16);
}

// ---------------- K1: A_lstm[b][k] = [relu(emb[ids[b]]) | ctx[b] | h0[b]] (bf16) ----------------
__global__ __launch_bounds__(256) void k_build_A(
    const float* __restrict__ emb, const float* __restrict__ ctx,
    const float* __restrict__ h0, const int* __restrict__ ids,
    short* __restrict__ A) {
  int k = blockIdx.x * 256 + threadIdx.x;   // 0..1535
  int b = blockIdx.y;
  float v;
  if (k < 512) {
    v = emb[(size_t)ids[b] * H + k];
    v = v > 0.f ? v : 0.f;
  } else if (k < 1024) {
    v = ctx[b * H + (k - 512)];
  } else {
    v = h0[b * H + (k - 1024)];
  }
  A[b * H3 + k] = bf16c(v);
}

// ---------------- K2: LSTM gates via MFMA. grid 128 (16 j-cols each), 4 waves k-split ----------------
__global__ __launch_bounds__(256) void k_lstm_gates_mfma(
    const short* __restrict__ A, const float* __restrict__ W_ih,
    const float* __restrict__ W_hh, const float* __restrict__ b_ih,
    const float* __restrict__ b_hh, float* __restrict__ gates) {
  __shared__ float sred[3][64][16];
  const int tid = threadIdx.x;
  const int lane = tid & 63, wid = tid >> 6;
  const int col = lane & 15, g = lane >> 4;
  const int j = blockIdx.x * 16 + col;      // gate-row 0..2047
  const int kbase = wid * 384;

  f32x4 acc[4];
  #pragma unroll
  for (int t = 0; t < 4; ++t) acc[t] = (f32x4)(0.f);

  #pragma unroll 2
  for (int it = 0; it < 12; ++it) {
    int k0 = kbase + it * 32;
    const float* wp;
    if (k0 < 1024) wp = W_ih + (size_t)j * H2 + k0 + g * 8;
    else           wp = W_hh + (size_t)j * H + (k0 - 1024) + g * 8;
    float4 wa = *(const float4*)wp;
    float4 wb = *(const float4*)(wp + 4);
    short8 bf;
    bf[0] = bf16c(wa.x); bf[1] = bf16c(wa.y); bf[2] = bf16c(wa.z); bf[3] = bf16c(wa.w);
    bf[4] = bf16c(wb.x); bf[5] = bf16c(wb.y); bf[6] = bf16c(wb.z); bf[7] = bf16c(wb.w);
    #pragma unroll
    for (int t = 0; t < 4; ++t) {
      short8 af = *(const short8*)(A + (size_t)(col + t * 16) * H3 + k0 + g * 8);
      acc[t] = __builtin_amdgcn_mfma_f32_16x16x32_bf16(af, bf, acc[t], 0, 0, 0);
    }
  }

  if (wid) {
    #pragma unroll
    for (int t = 0; t < 4; ++t)
      #pragma unroll
      for (int r = 0; r < 4; ++r) sred[wid - 1][lane][t * 4 + r] = acc[t][r];
  }
  __syncthreads();
  if (wid == 0) {
    float bias = b_ih[j] + b_hh[j];
    #pragma unroll
    for (int t = 0; t < 4; ++t)
      #pragma unroll
      for (int r = 0; r < 4; ++r) {
        float s = acc[t][r] + sred[0][lane][t * 4 + r] + sred[1][lane][t * 4 + r] +
                  sred[2][lane][t * 4 + r];
        int brow = t * 16 + g * 4 + r;
        gates[brow * H4 + j] = s + bias;
      }
  }
}

// ---------------- K3: LSTM cell elementwise (+ h1 bf16 copy) ----------------
__global__ __launch_bounds__(256) void k_lstm_cell(
    const float* __restrict__ gates, const float* __restrict__ c0,
    float* __restrict__ h1, float* __restrict__ c1, short* __restrict__ h1bf) {
  int idx = blockIdx.x * 256 + threadIdx.x;  // B*H
  int b = idx >> 9, h = idx & 511;
  const float* g = gates + b * H4;
  float gi = g[h], gf = g[H + h], gg = g[2 * H + h], go = g[3 * H + h];
  float c = sigf(gf) * c0[idx] + sigf(gi) * tanhf(gg);
  c1[idx] = c;
  float hv = sigf(go) * tanhf(c);
  h1[idx] = hv;
  h1bf[idx] = bf16c(hv);
}

// ---------------- K4: attn[b][m] = m_emb[mt[m][b]] . h1[b] ----------------
__global__ __launch_bounds__(256) void k_attn_scores(
    const float* __restrict__ m_emb, const int* __restrict__ mt,
    const float* __restrict__ h1, float* __restrict__ attn) {
  int wave = (blockIdx.x * 256 + threadIdx.x) >> 6;
  int lane = threadIdx.x & 63;
  int m = wave >> 6, b = wave & 63;
  int row = mt[m * B + b];
  const float4* e = (const float4*)(m_emb + (size_t)row * H);
  const float4* hv = (const float4*)(h1 + b * H);
  float4 a0 = e[lane], a1 = e[64 + lane];
  float4 b0 = hv[lane], b1 = hv[64 + lane];
  float acc = a0.x * b0.x + a0.y * b0.y + a0.z * b0.z + a0.w * b0.w +
              a1.x * b1.x + a1.y * b1.y + a1.z * b1.z + a1.w * b1.w;
  for (int off = 32; off > 0; off >>= 1) acc += __shfl_down(acc, off);
  if (lane == 0) attn[b * M + m] = acc;
}

// ---------------- K5: attn2 = attn @ attn_W^T + attn_b; log_softmax ----------------
__global__ __launch_bounds__(256) void k_attn_lin_lsm(
    const float* __restrict__ attn, const float* __restrict__ attn_W,
    const float* __restrict__ attn_b, float* __restrict__ attn_d) {
  __shared__ float arow[M];
  __shared__ float vals[256];
  __shared__ float red[256];
  int b = blockIdx.x, tid = threadIdx.x;
  if (tid < M) arow[tid] = attn[b * M + tid];
  __syncthreads();
  float v = -1e30f;
  if (tid < M) {
    const float* w = attn_W + tid * M;
    float a0 = attn_b[tid], a1 = 0.f;
    for (int m = 0; m < M; m += 2) {
      a0 = fmaf(arow[m], w[m], a0);
      a1 = fmaf(arow[m + 1], w[m + 1], a1);
    }
    v = a0 + a1;
  }
  vals[tid] = v;
  red[tid] = v;
  __syncthreads();
  for (int off = 128; off > 0; off >>= 1) {
    if (tid < off) red[tid] = fmaxf(red[tid], red[tid + off]);
    __syncthreads();
  }
  float mx = red[0];
  __syncthreads();
  red[tid] = (tid < M) ? expf(vals[tid] - mx) : 0.f;
  __syncthreads();
  for (int off = 128; off > 0; off >>= 1) {
    if (tid < off) red[tid] += red[tid + off];
    __syncthreads();
  }
  float lse = mx + logf(red[0]);
  if (tid < M) attn_d[b * M + tid] = vals[tid] - lse;
}

// ---------------- K6: memory_context partial sums over 4 m-chunks of 50 ----------------
__global__ __launch_bounds__(256) void k_mem_ctx_partial(
    const float* __restrict__ c_emb, const int* __restrict__ mt,
    const float* __restrict__ attn_d, float* __restrict__ mcp) {
  int b = blockIdx.x;     // 64
  int chunk = blockIdx.y; // 4
  int tid = threadIdx.x;  // 256
  __shared__ int rows[50];
  __shared__ float w[50];
  if (tid < 50) {
    int m = chunk * 50 + tid;
    rows[tid] = mt[m * B + b];
    w[tid] = attn_d[b * M + m];
  }
  __syncthreads();
  float acc0 = 0.f, acc1 = 0.f;
  #pragma unroll 5
  for (int i = 0; i < 50; ++i) {
    const float* e = c_emb + (size_t)rows[i] * H;
    acc0 = fmaf(w[i], e[tid], acc0);
    acc1 = fmaf(w[i], e[256 + tid], acc1);
  }
  mcp[(chunk * B + b) * H + tid] = acc0;
  mcp[(chunk * B + b) * H + 256 + tid] = acc1;
}

// K6b: reduce partials -> mc bf16
__global__ __launch_bounds__(256) void k_mem_ctx_reduce(
    const float* __restrict__ mcp, short* __restrict__ mcbf) {
  int idx = blockIdx.x * 256 + threadIdx.x;  // B*H
  float s = 0.f;
  for (int c = 0; c < 4; ++c) s += mcp[c * (B * H) + idx];
  mcbf[idx] = bf16c(s);
}

// ---------------- K7: GRU gates via MFMA. grid 192: half (gi/gh) x 96 col-tiles ----------------
__global__ __launch_bounds__(256) void k_gru_gates_mfma(
    const short* __restrict__ mcbf, const short* __restrict__ h1bf,
    const float* __restrict__ W_ih, const float* __restrict__ W_hh,
    const float* __restrict__ b_ih, const float* __restrict__ b_hh,
    float* __restrict__ gi, float* __restrict__ gh) {
  __shared__ float sred[3][64][16];
  const int tid = threadIdx.x;
  const int lane = tid & 63, wid = tid >> 6;
  const int col = lane & 15, g = lane >> 4;
  const int half = blockIdx.x / 96;
  const int j = (blockIdx.x % 96) * 16 + col;   // 0..1535
  const short* A = half ? h1bf : mcbf;
  const float* W = half ? W_hh : W_ih;
  const float* bias = half ? b_hh : b_ih;
  float* out = half ? gh : gi;
  const int kbase = wid * 128;

  f32x4 acc[4];
  #pragma unroll
  for (int t = 0; t < 4; ++t) acc[t] = (f32x4)(0.f);

  #pragma unroll
  for (int it = 0; it < 4; ++it) {
    int k0 = kbase + it * 32;
    const float* wp = W + (size_t)j * H + k0 + g * 8;
    float4 wa = *(const float4*)wp;
    float4 wb = *(const float4*)(wp + 4);
    short8 bf;
    bf[0] = bf16c(wa.x); bf[1] = bf16c(wa.y); bf[2] = bf16c(wa.z); bf[3] = bf16c(wa.w);
    bf[4] = bf16c(wb.x); bf[5] = bf16c(wb.y); bf[6] = bf16c(wb.z); bf[7] = bf16c(wb.w);
    #pragma unroll
    for (int t = 0; t < 4; ++t) {
      short8 af = *(const short8*)(A + (size_t)(col + t * 16) * H + k0 + g * 8);
      acc[t] = __builtin_amdgcn_mfma_f32_16x16x32_bf16(af, bf, acc[t], 0, 0, 0);
    }
  }

  if (wid) {
    #pragma unroll
    for (int t = 0; t < 4; ++t)
      #pragma unroll
      for (int r = 0; r < 4; ++r) sred[wid - 1][lane][t * 4 + r] = acc[t][r];
  }
  __syncthreads();
  if (wid == 0) {
    float bv = bias[j];
    #pragma unroll
    for (int t = 0; t < 4; ++t)
      #pragma unroll
      for (int r = 0; r < 4; ++r) {
        float s = acc[t][r] + sred[0][lane][t * 4 + r] + sred[1][lane][t * 4 + r] +
                  sred[2][lane][t * 4 + r];
        int brow = t * 16 + g * 4 + r;
        out[brow * H3 + j] = s + bv;
      }
  }
}

// ---------------- K8: GRU combine + build A (bf16) = [mb, ctx] ----------------
__global__ __launch_bounds__(256) void k_gru_combine(
    const float* __restrict__ gi, const float* __restrict__ gh,
    const float* __restrict__ h1, const float* __restrict__ ctx,
    short* __restrict__ Abf) {
  int idx = blockIdx.x * 256 + threadIdx.x;  // B*H
  int b = idx >> 9, h = idx & 511;
  const float* gib = gi + b * H3;
  const float* ghb = gh + b * H3;
  float r = sigf(gib[h] + ghb[h]);
  float z = sigf(gib[H + h] + ghb[H + h]);
  float n = tanhf(gib[2 * H + h] + r * ghb[2 * H + h]);
  float mb = (1.f - z) * n + z * h1[idx];
  Abf[b * H2 + h] = bf16c(mb);
  Abf[b * H2 + H + h] = bf16c(ctx[idx]);
}

// ---------------- K9: logits = A @ W^T + bias (MFMA) + per-block LSE partials ----------------
__global__ __launch_bounds__(256) void k_out_gemm_mfma(
    const short* __restrict__ Abf, const float* __restrict__ W,
    const float* __restrict__ bias, float* __restrict__ out,
    float* __restrict__ pm, float* __restrict__ ps) {
  __shared__ float spm[4][64];
  __shared__ float sps[4][64];
  const int tid = threadIdx.x;
  const int lane = tid & 63;
  const int wid = tid >> 6;
  const int col = lane & 15;
  const int g = lane >> 4;

  const int v = blockIdx.x * 64 + wid * 16 + col;
  const int vc = v < V ? v : V - 1;

  const float* wp = W + (size_t)vc * H2 + g * 8;
  const short* ap = Abf + col * H2 + g * 8;

  f32x4 acc[4];
  #pragma unroll
  for (int t = 0; t < 4; ++t) acc[t] = (f32x4)(0.f);

  #pragma unroll 2
  for (int k0 = 0; k0 < H2; k0 += 32) {
    float4 wa = *(const float4*)(wp + k0);
    float4 wb = *(const float4*)(wp + k0 + 4);
    short8 bf;
    bf[0] = bf16c(wa.x); bf[1] = bf16c(wa.y); bf[2] = bf16c(wa.z); bf[3] = bf16c(wa.w);
    bf[4] = bf16c(wb.x); bf[5] = bf16c(wb.y); bf[6] = bf16c(wb.z); bf[7] = bf16c(wb.w);
    #pragma unroll
    for (int t = 0; t < 4; ++t) {
      short8 af = *(const short8*)(ap + t * 16 * H2 + k0);
      acc[t] = __builtin_amdgcn_mfma_f32_16x16x32_bf16(af, bf, acc[t], 0, 0, 0);
    }
  }

  const float bv = v < V ? bias[v] : 0.f;
  #pragma unroll
  for (int t = 0; t < 4; ++t) {
    #pragma unroll
    for (int r = 0; r < 4; ++r) {
      int brow = t * 16 + g * 4 + r;
      float x = acc[t][r] + bv;
      float xm = v < V ? x : -1e30f;
      if (v < V) out[(size_t)brow * V + v] = x;
      // reduce over the 16 col lanes of this group
      float mx = xm;
      #pragma unroll
      for (int off = 1; off < 16; off <<= 1) mx = fmaxf(mx, __shfl_xor(mx, off));
      float e = v < V ? expf(xm - mx) : 0.f;
      #pragma unroll
      for (int off = 1; off < 16; off <<= 1) e += __shfl_xor(e, off);
      if (col == 0) {
        spm[wid][brow] = mx;
        sps[wid][brow] = e;
      }
    }
  }
  __syncthreads();
  if (tid < 64) {
    float m = spm[0][tid], s = sps[0][tid];
    #pragma unroll
    for (int w = 1; w < 4; ++w) {
      float m2 = spm[w][tid], s2 = sps[w][tid];
      float nm = fmaxf(m, m2);
      s = s * expf(m - nm) + s2 * expf(m2 - nm);
      m = nm;
    }
    pm[(size_t)tid * NB + blockIdx.x] = m;
    ps[(size_t)tid * NB + blockIdx.x] = s;
  }
}

// ---------------- K10: combine partials -> lse[b] ----------------
__global__ __launch_bounds__(256) void k_lsm_finalize(
    const float* __restrict__ pm, const float* __restrict__ ps,
    float* __restrict__ lse) {
  int b = blockIdx.x, tid = threadIdx.x;
  float m = -1e30f, s = 0.f;
  for (int gq = tid; gq < NB; gq += 256) {
    float m2 = pm[(size_t)b * NB + gq], s2 = ps[(size_t)b * NB + gq];
    float nm = fmaxf(m, m2);
    s = s * expf(m - nm) + s2 * expf(m2 - nm);
    m = nm;
  }
  __shared__ float sm[256], ss[256];
  sm[tid] = m; ss[tid] = s;
  __syncthreads();
  for (int off = 128; off > 0; off >>= 1) {
    if (tid < off) {
      float m1 = sm[tid], s1 = ss[tid];
      float m2 = sm[tid + off], s2 = ss[tid + off];
      float nm = fmaxf(m1, m2);
      sm[tid] = nm;
      ss[tid] = s1 * expf(m1 - nm) + s2 * expf(m2 - nm);
    }
    __syncthreads();
  }
  if (tid == 0) lse[b] = sm[0] + logf(ss[0]);
}

// ---------------- K11: out -= lse[b]. grid (50, B) ----------------
__global__ __launch_bounds__(256) void k_lsm_apply(
    float* __restrict__ out, const float* __restrict__ lse) {
  int b = blockIdx.y, tid = threadIdx.x;
  float l = lse[b];
  int v = blockIdx.x * 1024 + tid * 4;
  float* row = out + (size_t)b * V;
  if (v + 3 < V) {
    float4 x = *(const float4*)(row + v);
    x.x -= l; x.y -= l; x.z -= l; x.w -= l;
    *(float4*)(row + v) = x;
  } else {
    for (int i = 0; i < 4 && v + i < V; ++i) row[v + i] -= l;
  }
}

extern "C" void kernel_launch(void* const* d_in, const int* in_sizes, int n_in,
                              void* d_out, int out_size, void* d_ws, size_t ws_size,
                              hipStream_t stream) {
  const float* h0    = (const float*)d_in[0];
  const float* c0    = (const float*)d_in[1];
  const float* ctx   = (const float*)d_in[2];
  const float* emb   = (const float*)d_in[3];
  const float* m_emb = (const float*)d_in[4];
  const float* c_emb = (const float*)d_in[5];
  const float* lWih  = (const float*)d_in[6];
  const float* lWhh  = (const float*)d_in[7];
  const float* lbih  = (const float*)d_in[8];
  const float* lbhh  = (const float*)d_in[9];
  const float* gWih  = (const float*)d_in[10];
  const float* gWhh  = (const float*)d_in[11];
  const float* gbih  = (const float*)d_in[12];
  const float* gbhh  = (const float*)d_in[13];
  const float* aW    = (const float*)d_in[14];
  const float* ab    = (const float*)d_in[15];
  const float* oW    = (const float*)d_in[16];
  const float* ob    = (const float*)d_in[17];
  const int* ids     = (const int*)d_in[18];
  const int* mt      = (const int*)d_in[19];

  float* out = (float*)d_out;
  float* h1  = out + (size_t)B * V;
  float* c1  = h1 + B * H;

  // Workspace layout — all offsets in FLOAT units, bf16 buffers counted as
  // ceil(shorts/2) floats. Total = 699,712 floats = 2.80 MB.
  float* ws    = (float*)d_ws;
  short* Albf  = (short*)ws;                   // 64*1536 shorts = 49152 fl
  float* gates = ws + 49152;                   // B*H4 = 131072 fl
  short* h1bf  = (short*)(gates + B * H4);     // 64*512 shorts = 16384 fl
  float* attn  = gates + B * H4 + 16384;       // B*M = 12800 fl
  float* attnd = attn + B * M;                 // 12800 fl
  float* mcp   = attnd + B * M;                // 4*B*H = 131072 fl
  short* mcbf  = (short*)(mcp + 4 * B * H);    // 64*512 shorts = 16384 fl
  float* gi    = mcp + 4 * B * H + 16384;      // B*H3 = 98304 fl
  float* gh    = gi + B * H3;                  // 98304 fl
  short* Abf   = (short*)(gh + B * H3);        // 64*1024 shorts = 32768 fl
  float* pm    = gh + B * H3 + 32768;          // B*NB = 50304 fl
  float* ps    = pm + (size_t)B * NB;          // 50304 fl
  float* lse   = ps + (size_t)B * NB;          // 64 fl

  dim3 g1(6, B);
  k_build_A<<<g1, 256, 0, stream>>>(emb, ctx, h0, ids, Albf);
  k_lstm_gates_mfma<<<128, 256, 0, stream>>>(Albf, lWih, lWhh, lbih, lbhh, gates);
  k_lstm_cell<<<(B * H) / 256, 256, 0, stream>>>(gates, c0, h1, c1, h1bf);
  k_attn_scores<<<(M * B) / 4, 256, 0, stream>>>(m_emb, mt, h1, attn);
  k_attn_lin_lsm<<<B, 256, 0, stream>>>(attn, aW, ab, attnd);
  dim3 g6(B, 4);
  k_mem_ctx_partial<<<g6, 256, 0, stream>>>(c_emb, mt, attnd, mcp);
  k_mem_ctx_reduce<<<(B * H) / 256, 256, 0, stream>>>(mcp, mcbf);
  k_gru_gates_mfma<<<192, 256, 0, stream>>>(mcbf, h1bf, gWih, gWhh, gbih, gbhh, gi, gh);
  k_gru_combine<<<(B * H) / 256, 256, 0, stream>>>(gi, gh, h1, ctx, Abf);
  k_out_gemm_mfma<<<NB, 256, 0, stream>>>(Abf, oW, ob, out, pm, ps);
  k_lsm_finalize<<<B, 256, 0, stream>>>(pm, ps, lse);
  dim3 g11(50, B);
  k_lsm_apply<<<g11, 256, 0, stream>>>(out, lse);
}

// Round 5
// 153.424 us; speedup vs baseline: 2.7295x; 1.0519x over previous
//
#include <hip/hip_runtime.h>
#include <math.h>

#define B 64
#define H 512
#define V 50257
#define M 200
#define H2 1024
#define H3 1536
#define H4 2048
#define NBK 3142           // ceil(V/16) = number of out-GEMM blocks

typedef short short8 __attribute__((ext_vector_type(8)));
typedef float f32x4 __attribute__((ext_vector_type(4)));

__device__ __forceinline__ float sigf(float x) { return 1.f / (1.f + expf(-x)); }

// f32 -> bf16 (RNE) as raw short
__device__ __forceinline__ short bf16c(float f) {
  unsigned u = __builtin_bit_cast(unsigned, f);
  unsigned r = u + 0x7fffu + ((u >> 16) & 1u);
  return (short)(r >> 16);
}

// ---------------- K1: A_lstm[b][k] = [relu(emb[ids[b]]) | ctx[b] | h0[b]] (bf16) ----------------
__global__ __launch_bounds__(256) void k_build_A(
    const float* __restrict__ emb, const float* __restrict__ ctx,
    const float* __restrict__ h0, const int* __restrict__ ids,
    short* __restrict__ A) {
  int k = blockIdx.x * 256 + threadIdx.x;   // 0..1535
  int b = blockIdx.y;
  float v;
  if (k < 512) {
    v = emb[(size_t)ids[b] * H + k];
    v = v > 0.f ? v : 0.f;
  } else if (k < 1024) {
    v = ctx[b * H + (k - 512)];
  } else {
    v = h0[b * H + (k - 1024)];
  }
  A[b * H3 + k] = bf16c(v);
}

// ---------------- K2: LSTM gates via MFMA. grid 128 (16 j-cols each), 4 waves k-split ----------------
__global__ __launch_bounds__(256) void k_lstm_gates_mfma(
    const short* __restrict__ A, const float* __restrict__ W_ih,
    const float* __restrict__ W_hh, const float* __restrict__ b_ih,
    const float* __restrict__ b_hh, float* __restrict__ gates) {
  __shared__ float sred[3][64][16];
  const int tid = threadIdx.x;
  const int lane = tid & 63, wid = tid >> 6;
  const int col = lane & 15, g = lane >> 4;
  const int j = blockIdx.x * 16 + col;      // gate-row 0..2047
  const int kbase = wid * 384;

  f32x4 acc[4];
  #pragma unroll
  for (int t = 0; t < 4; ++t) acc[t] = (f32x4)(0.f);

  #pragma unroll 2
  for (int it = 0; it < 12; ++it) {
    int k0 = kbase + it * 32;
    const float* wp;
    if (k0 < 1024) wp = W_ih + (size_t)j * H2 + k0 + g * 8;
    else           wp = W_hh + (size_t)j * H + (k0 - 1024) + g * 8;
    float4 wa = *(const float4*)wp;
    float4 wb = *(const float4*)(wp + 4);
    short8 bf;
    bf[0] = bf16c(wa.x); bf[1] = bf16c(wa.y); bf[2] = bf16c(wa.z); bf[3] = bf16c(wa.w);
    bf[4] = bf16c(wb.x); bf[5] = bf16c(wb.y); bf[6] = bf16c(wb.z); bf[7] = bf16c(wb.w);
    #pragma unroll
    for (int t = 0; t < 4; ++t) {
      short8 af = *(const short8*)(A + (size_t)(col + t * 16) * H3 + k0 + g * 8);
      acc[t] = __builtin_amdgcn_mfma_f32_16x16x32_bf16(af, bf, acc[t], 0, 0, 0);
    }
  }

  if (wid) {
    #pragma unroll
    for (int t = 0; t < 4; ++t)
      #pragma unroll
      for (int r = 0; r < 4; ++r) sred[wid - 1][lane][t * 4 + r] = acc[t][r];
  }
  __syncthreads();
  if (wid == 0) {
    float bias = b_ih[j] + b_hh[j];
    #pragma unroll
    for (int t = 0; t < 4; ++t)
      #pragma unroll
      for (int r = 0; r < 4; ++r) {
        float s = acc[t][r] + sred[0][lane][t * 4 + r] + sred[1][lane][t * 4 + r] +
                  sred[2][lane][t * 4 + r];
        int brow = t * 16 + g * 4 + r;
        gates[brow * H4 + j] = s + bias;
      }
  }
}

// ---------------- K3: LSTM cell elementwise (+ h1 bf16 copy) ----------------
__global__ __launch_bounds__(256) void k_lstm_cell(
    const float* __restrict__ gates, const float* __restrict__ c0,
    float* __restrict__ h1, float* __restrict__ c1, short* __restrict__ h1bf) {
  int idx = blockIdx.x * 256 + threadIdx.x;  // B*H
  int b = idx >> 9, h = idx & 511;
  const float* g = gates + b * H4;
  float gi = g[h], gf = g[H + h], gg = g[2 * H + h], go = g[3 * H + h];
  float c = sigf(gf) * c0[idx] + sigf(gi) * tanhf(gg);
  c1[idx] = c;
  float hv = sigf(go) * tanhf(c);
  h1[idx] = hv;
  h1bf[idx] = bf16c(hv);
}

// ---------------- K4: attn[b][m] = m_emb[mt[m][b]] . h1[b] ----------------
__global__ __launch_bounds__(256) void k_attn_scores(
    const float* __restrict__ m_emb, const int* __restrict__ mt,
    const float* __restrict__ h1, float* __restrict__ attn) {
  int wave = (blockIdx.x * 256 + threadIdx.x) >> 6;
  int lane = threadIdx.x & 63;
  int m = wave >> 6, b = wave & 63;
  int row = mt[m * B + b];
  const float4* e = (const float4*)(m_emb + (size_t)row * H);
  const float4* hv = (const float4*)(h1 + b * H);
  float4 a0 = e[lane], a1 = e[64 + lane];
  float4 b0 = hv[lane], b1 = hv[64 + lane];
  float acc = a0.x * b0.x + a0.y * b0.y + a0.z * b0.z + a0.w * b0.w +
              a1.x * b1.x + a1.y * b1.y + a1.z * b1.z + a1.w * b1.w;
  for (int off = 32; off > 0; off >>= 1) acc += __shfl_down(acc, off);
  if (lane == 0) attn[b * M + m] = acc;
}

// ---------------- K5: attn2 = attn @ attn_W^T + attn_b; log_softmax ----------------
__global__ __launch_bounds__(256) void k_attn_lin_lsm(
    const float* __restrict__ attn, const float* __restrict__ attn_W,
    const float* __restrict__ attn_b, float* __restrict__ attn_d) {
  __shared__ float arow[M];
  __shared__ float vals[256];
  __shared__ float red[256];
  int b = blockIdx.x, tid = threadIdx.x;
  if (tid < M) arow[tid] = attn[b * M + tid];
  __syncthreads();
  float v = -1e30f;
  if (tid < M) {
    const float* w = attn_W + tid * M;
    float a0 = attn_b[tid], a1 = 0.f;
    for (int m = 0; m < M; m += 2) {
      a0 = fmaf(arow[m], w[m], a0);
      a1 = fmaf(arow[m + 1], w[m + 1], a1);
    }
    v = a0 + a1;
  }
  vals[tid] = v;
  red[tid] = v;
  __syncthreads();
  for (int off = 128; off > 0; off >>= 1) {
    if (tid < off) red[tid] = fmaxf(red[tid], red[tid + off]);
    __syncthreads();
  }
  float mx = red[0];
  __syncthreads();
  red[tid] = (tid < M) ? expf(vals[tid] - mx) : 0.f;
  __syncthreads();
  for (int off = 128; off > 0; off >>= 1) {
    if (tid < off) red[tid] += red[tid + off];
    __syncthreads();
  }
  float lse = mx + logf(red[0]);
  if (tid < M) attn_d[b * M + tid] = vals[tid] - lse;
}

// ---------------- K6: memory_context partial sums over 4 m-chunks of 50 ----------------
__global__ __launch_bounds__(256) void k_mem_ctx_partial(
    const float* __restrict__ c_emb, const int* __restrict__ mt,
    const float* __restrict__ attn_d, float* __restrict__ mcp) {
  int b = blockIdx.x;     // 64
  int chunk = blockIdx.y; // 4
  int tid = threadIdx.x;  // 256
  __shared__ int rows[50];
  __shared__ float w[50];
  if (tid < 50) {
    int m = chunk * 50 + tid;
    rows[tid] = mt[m * B + b];
    w[tid] = attn_d[b * M + m];
  }
  __syncthreads();
  float acc0 = 0.f, acc1 = 0.f;
  #pragma unroll 5
  for (int i = 0; i < 50; ++i) {
    const float* e = c_emb + (size_t)rows[i] * H;
    acc0 = fmaf(w[i], e[tid], acc0);
    acc1 = fmaf(w[i], e[256 + tid], acc1);
  }
  mcp[(chunk * B + b) * H + tid] = acc0;
  mcp[(chunk * B + b) * H + 256 + tid] = acc1;
}

// K6b: reduce partials -> mc bf16
__global__ __launch_bounds__(256) void k_mem_ctx_reduce(
    const float* __restrict__ mcp, short* __restrict__ mcbf) {
  int idx = blockIdx.x * 256 + threadIdx.x;  // B*H
  float s = 0.f;
  for (int c = 0; c < 4; ++c) s += mcp[c * (B * H) + idx];
  mcbf[idx] = bf16c(s);
}

// ---------------- K7: GRU gates via MFMA. grid 192: half (gi/gh) x 96 col-tiles ----------------
__global__ __launch_bounds__(256) void k_gru_gates_mfma(
    const short* __restrict__ mcbf, const short* __restrict__ h1bf,
    const float* __restrict__ W_ih, const float* __restrict__ W_hh,
    const float* __restrict__ b_ih, const float* __restrict__ b_hh,
    float* __restrict__ gi, float* __restrict__ gh) {
  __shared__ float sred[3][64][16];
  const int tid = threadIdx.x;
  const int lane = tid & 63, wid = tid >> 6;
  const int col = lane & 15, g = lane >> 4;
  const int half = blockIdx.x / 96;
  const int j = (blockIdx.x % 96) * 16 + col;   // 0..1535
  const short* A = half ? h1bf : mcbf;
  const float* W = half ? W_hh : W_ih;
  const float* bias = half ? b_hh : b_ih;
  float* out = half ? gh : gi;
  const int kbase = wid * 128;

  f32x4 acc[4];
  #pragma unroll
  for (int t = 0; t < 4; ++t) acc[t] = (f32x4)(0.f);

  #pragma unroll
  for (int it = 0; it < 4; ++it) {
    int k0 = kbase + it * 32;
    const float* wp = W + (size_t)j * H + k0 + g * 8;
    float4 wa = *(const float4*)wp;
    float4 wb = *(const float4*)(wp + 4);
    short8 bf;
    bf[0] = bf16c(wa.x); bf[1] = bf16c(wa.y); bf[2] = bf16c(wa.z); bf[3] = bf16c(wa.w);
    bf[4] = bf16c(wb.x); bf[5] = bf16c(wb.y); bf[6] = bf16c(wb.z); bf[7] = bf16c(wb.w);
    #pragma unroll
    for (int t = 0; t < 4; ++t) {
      short8 af = *(const short8*)(A + (size_t)(col + t * 16) * H + k0 + g * 8);
      acc[t] = __builtin_amdgcn_mfma_f32_16x16x32_bf16(af, bf, acc[t], 0, 0, 0);
    }
  }

  if (wid) {
    #pragma unroll
    for (int t = 0; t < 4; ++t)
      #pragma unroll
      for (int r = 0; r < 4; ++r) sred[wid - 1][lane][t * 4 + r] = acc[t][r];
  }
  __syncthreads();
  if (wid == 0) {
    float bv = bias[j];
    #pragma unroll
    for (int t = 0; t < 4; ++t)
      #pragma unroll
      for (int r = 0; r < 4; ++r) {
        float s = acc[t][r] + sred[0][lane][t * 4 + r] + sred[1][lane][t * 4 + r] +
                  sred[2][lane][t * 4 + r];
        int brow = t * 16 + g * 4 + r;
        out[brow * H3 + j] = s + bv;
      }
  }
}

// ---------------- K8: GRU combine + build A (bf16) = [mb, ctx] ----------------
__global__ __launch_bounds__(256) void k_gru_combine(
    const float* __restrict__ gi, const float* __restrict__ gh,
    const float* __restrict__ h1, const float* __restrict__ ctx,
    short* __restrict__ Abf) {
  int idx = blockIdx.x * 256 + threadIdx.x;  // B*H
  int b = idx >> 9, h = idx & 511;
  const float* gib = gi + b * H3;
  const float* ghb = gh + b * H3;
  float r = sigf(gib[h] + ghb[h]);
  float z = sigf(gib[H + h] + ghb[H + h]);
  float n = tanhf(gib[2 * H + h] + r * ghb[2 * H + h]);
  float mb = (1.f - z) * n + z * h1[idx];
  Abf[b * H2 + h] = bf16c(mb);
  Abf[b * H2 + H + h] = bf16c(ctx[idx]);
}

// ---------------- K9: logits = A @ W^T + bias (MFMA, 4-wave k-split) + LSE partials ----------------
// grid NBK=3142 blocks; each block: 16 vocab cols, 4 waves each own a K-quarter (256).
__global__ __launch_bounds__(256) void k_out_gemm_mfma(
    const short* __restrict__ Abf, const float* __restrict__ W,
    const float* __restrict__ bias, float* __restrict__ out,
    float* __restrict__ pm, float* __restrict__ ps) {
  __shared__ float sred[3][64][16];
  const int tid = threadIdx.x;
  const int lane = tid & 63;
  const int wid = tid >> 6;
  const int col = lane & 15;
  const int g = lane >> 4;

  const int v = blockIdx.x * 16 + col;
  const int vc = v < V ? v : V - 1;
  const int kbase = wid * 256;

  const float* wp = W + (size_t)vc * H2 + kbase + g * 8;
  const short* ap = Abf + col * H2 + kbase + g * 8;

  f32x4 acc[4];
  #pragma unroll
  for (int t = 0; t < 4; ++t) acc[t] = (f32x4)(0.f);

  #pragma unroll 2
  for (int it = 0; it < 8; ++it) {
    int k0 = it * 32;
    float4 wa = *(const float4*)(wp + k0);
    float4 wb = *(const float4*)(wp + k0 + 4);
    short8 bf;
    bf[0] = bf16c(wa.x); bf[1] = bf16c(wa.y); bf[2] = bf16c(wa.z); bf[3] = bf16c(wa.w);
    bf[4] = bf16c(wb.x); bf[5] = bf16c(wb.y); bf[6] = bf16c(wb.z); bf[7] = bf16c(wb.w);
    #pragma unroll
    for (int t = 0; t < 4; ++t) {
      short8 af = *(const short8*)(ap + t * 16 * H2 + k0);
      acc[t] = __builtin_amdgcn_mfma_f32_16x16x32_bf16(af, bf, acc[t], 0, 0, 0);
    }
  }

  if (wid) {
    #pragma unroll
    for (int t = 0; t < 4; ++t)
      #pragma unroll
      for (int r = 0; r < 4; ++r) sred[wid - 1][lane][t * 4 + r] = acc[t][r];
  }
  __syncthreads();
  if (wid == 0) {
    const float bv = v < V ? bias[v] : 0.f;
    #pragma unroll
    for (int t = 0; t < 4; ++t) {
      #pragma unroll
      for (int r = 0; r < 4; ++r) {
        int brow = t * 16 + g * 4 + r;
        float x = acc[t][r] + sred[0][lane][t * 4 + r] + sred[1][lane][t * 4 + r] +
                  sred[2][lane][t * 4 + r] + bv;
        float xm = v < V ? x : -1e30f;
        if (v < V) out[(size_t)brow * V + v] = x;
        // reduce over the 16 col lanes of this group
        float mx = xm;
        #pragma unroll
        for (int off = 1; off < 16; off <<= 1) mx = fmaxf(mx, __shfl_xor(mx, off));
        float e = v < V ? expf(xm - mx) : 0.f;
        #pragma unroll
        for (int off = 1; off < 16; off <<= 1) e += __shfl_xor(e, off);
        if (col == 0) {
          pm[(size_t)brow * NBK + blockIdx.x] = mx;
          ps[(size_t)brow * NBK + blockIdx.x] = e;
        }
      }
    }
  }
}

// ---------------- K10: combine partials -> lse[b] ----------------
__global__ __launch_bounds__(256) void k_lsm_finalize(
    const float* __restrict__ pm, const float* __restrict__ ps,
    float* __restrict__ lse) {
  int b = blockIdx.x, tid = threadIdx.x;
  float m = -1e30f, s = 0.f;
  for (int gq = tid; gq < NBK; gq += 256) {
    float m2 = pm[(size_t)b * NBK + gq], s2 = ps[(size_t)b * NBK + gq];
    float nm = fmaxf(m, m2);
    s = s * expf(m - nm) + s2 * expf(m2 - nm);
    m = nm;
  }
  __shared__ float sm[256], ss[256];
  sm[tid] = m; ss[tid] = s;
  __syncthreads();
  for (int off = 128; off > 0; off >>= 1) {
    if (tid < off) {
      float m1 = sm[tid], s1 = ss[tid];
      float m2 = sm[tid + off], s2 = ss[tid + off];
      float nm = fmaxf(m1, m2);
      sm[tid] = nm;
      ss[tid] = s1 * expf(m1 - nm) + s2 * expf(m2 - nm);
    }
    __syncthreads();
  }
  if (tid == 0) lse[b] = sm[0] + logf(ss[0]);
}

// ---------------- K11: out -= lse[b]. grid (50, B) ----------------
__global__ __launch_bounds__(256) void k_lsm_apply(
    float* __restrict__ out, const float* __restrict__ lse) {
  int b = blockIdx.y, tid = threadIdx.x;
  float l = lse[b];
  int v = blockIdx.x * 1024 + tid * 4;
  float* row = out + (size_t)b * V;
  if (v + 3 < V) {
    float4 x = *(const float4*)(row + v);
    x.x -= l; x.y -= l; x.z -= l; x.w -= l;
    *(float4*)(row + v) = x;
  } else {
    for (int i = 0; i < 4 && v + i < V; ++i) row[v + i] -= l;
  }
}

extern "C" void kernel_launch(void* const* d_in, const int* in_sizes, int n_in,
                              void* d_out, int out_size, void* d_ws, size_t ws_size,
                              hipStream_t stream) {
  const float* h0    = (const float*)d_in[0];
  const float* c0    = (const float*)d_in[1];
  const float* ctx   = (const float*)d_in[2];
  const float* emb   = (const float*)d_in[3];
  const float* m_emb = (const float*)d_in[4];
  const float* c_emb = (const float*)d_in[5];
  const float* lWih  = (const float*)d_in[6];
  const float* lWhh  = (const float*)d_in[7];
  const float* lbih  = (const float*)d_in[8];
  const float* lbhh  = (const float*)d_in[9];
  const float* gWih  = (const float*)d_in[10];
  const float* gWhh  = (const float*)d_in[11];
  const float* gbih  = (const float*)d_in[12];
  const float* gbhh  = (const float*)d_in[13];
  const float* aW    = (const float*)d_in[14];
  const float* ab    = (const float*)d_in[15];
  const float* oW    = (const float*)d_in[16];
  const float* ob    = (const float*)d_in[17];
  const int* ids     = (const int*)d_in[18];
  const int* mt      = (const int*)d_in[19];

  float* out = (float*)d_out;
  float* h1  = out + (size_t)B * V;
  float* c1  = h1 + B * H;

  // Workspace layout — offsets in FLOAT units; bf16 buffers counted as shorts/2 floats.
  float* ws    = (float*)d_ws;
  short* Albf  = (short*)ws;                   // 64*1536 shorts = 49152 fl
  float* gates = ws + 49152;                   // B*H4 = 131072 fl
  short* h1bf  = (short*)(gates + B * H4);     // 64*512 shorts = 16384 fl
  float* attn  = gates + B * H4 + 16384;       // B*M = 12800 fl
  float* attnd = attn + B * M;                 // 12800 fl
  float* mcp   = attnd + B * M;                // 4*B*H = 131072 fl
  short* mcbf  = (short*)(mcp + 4 * B * H);    // 64*512 shorts = 16384 fl
  float* gi    = mcp + 4 * B * H + 16384;      // B*H3 = 98304 fl
  float* gh    = gi + B * H3;                  // 98304 fl
  short* Abf   = (short*)(gh + B * H3);        // 64*1024 shorts = 32768 fl
  float* pm    = gh + B * H3 + 32768;          // B*NBK = 201088 fl
  float* ps    = pm + (size_t)B * NBK;         // 201088 fl
  float* lse   = ps + (size_t)B * NBK;         // 64 fl

  dim3 g1(6, B);
  k_build_A<<<g1, 256, 0, stream>>>(emb, ctx, h0, ids, Albf);
  k_lstm_gates_mfma<<<128, 256, 0, stream>>>(Albf, lWih, lWhh, lbih, lbhh, gates);
  k_lstm_cell<<<(B * H) / 256, 256, 0, stream>>>(gates, c0, h1, c1, h1bf);
  k_attn_scores<<<(M * B) / 4, 256, 0, stream>>>(m_emb, mt, h1, attn);
  k_attn_lin_lsm<<<B, 256, 0, stream>>>(attn, aW, ab, attnd);
  dim3 g6(B, 4);
  k_mem_ctx_partial<<<g6, 256, 0, stream>>>(c_emb, mt, attnd, mcp);
  k_mem_ctx_reduce<<<(B * H) / 256, 256, 0, stream>>>(mcp, mcbf);
  k_gru_gates_mfma<<<192, 256, 0, stream>>>(mcbf, h1bf, gWih, gWhh, gbih, gbhh, gi, gh);
  k_gru_combine<<<(B * H) / 256, 256, 0, stream>>>(gi, gh, h1, ctx, Abf);
  k_out_gemm_mfma<<<NBK, 256, 0, stream>>>(Abf, oW, ob, out, pm, ps);
  k_lsm_finalize<<<B, 256, 0, stream>>>(pm, ps, lse);
  dim3 g11(50, B);
  k_lsm_apply<<<g11, 256, 0, stream>>>(out, lse);
}

// Round 6
// 110.746 us; speedup vs baseline: 3.7814x; 1.3854x over previous
//
#include <hip/hip_runtime.h>
#include <math.h>

#define B 64
#define H 512
#define V 50257
#define M 200
#define H2 1024
#define H3 1536
#define H4 2048
#define NB 786             // ceil(V/64) = out-GEMM blocks

typedef short short8 __attribute__((ext_vector_type(8)));
typedef float f32x4 __attribute__((ext_vector_type(4)));

__device__ __forceinline__ float sigf(float x) { return 1.f / (1.f + expf(-x)); }

// f32 -> bf16 (RNE) as raw short
__device__ __forceinline__ short bf16c(float f) {
  unsigned u = __builtin_bit_cast(unsigned, f);
  unsigned r = u + 0x7fffu + ((u >> 16) & 1u);
  return (short)(r >> 16);
}

// ---------------- K1: A_lstm[b][k] = [relu(emb[ids[b]]) | ctx[b] | h0[b]] (bf16) ----------------
__global__ __launch_bounds__(256) void k_build_A(
    const float* __restrict__ emb, const float* __restrict__ ctx,
    const float* __restrict__ h0, const int* __restrict__ ids,
    short* __restrict__ A) {
  int k = blockIdx.x * 256 + threadIdx.x;   // 0..1535
  int b = blockIdx.y;
  float v;
  if (k < 512) {
    v = emb[(size_t)ids[b] * H + k];
    v = v > 0.f ? v : 0.f;
  } else if (k < 1024) {
    v = ctx[b * H + (k - 512)];
  } else {
    v = h0[b * H + (k - 1024)];
  }
  A[b * H3 + k] = bf16c(v);
}

// ---------------- K2: LSTM gates via MFMA. grid 128 (16 j-cols each), 4 waves k-split ----------------
__global__ __launch_bounds__(256) void k_lstm_gates_mfma(
    const short* __restrict__ A, const float* __restrict__ W_ih,
    const float* __restrict__ W_hh, const float* __restrict__ b_ih,
    const float* __restrict__ b_hh, float* __restrict__ gates) {
  __shared__ float sred[3][64][16];
  const int tid = threadIdx.x;
  const int lane = tid & 63, wid = tid >> 6;
  const int col = lane & 15, g = lane >> 4;
  const int j = blockIdx.x * 16 + col;      // gate-row 0..2047
  const int kbase = wid * 384;

  f32x4 acc[4];
  #pragma unroll
  for (int t = 0; t < 4; ++t) acc[t] = (f32x4)(0.f);

  #pragma unroll 2
  for (int it = 0; it < 12; ++it) {
    int k0 = kbase + it * 32;
    const float* wp;
    if (k0 < 1024) wp = W_ih + (size_t)j * H2 + k0 + g * 8;
    else           wp = W_hh + (size_t)j * H + (k0 - 1024) + g * 8;
    float4 wa = *(const float4*)wp;
    float4 wb = *(const float4*)(wp + 4);
    short8 bf;
    bf[0] = bf16c(wa.x); bf[1] = bf16c(wa.y); bf[2] = bf16c(wa.z); bf[3] = bf16c(wa.w);
    bf[4] = bf16c(wb.x); bf[5] = bf16c(wb.y); bf[6] = bf16c(wb.z); bf[7] = bf16c(wb.w);
    #pragma unroll
    for (int t = 0; t < 4; ++t) {
      short8 af = *(const short8*)(A + (size_t)(col + t * 16) * H3 + k0 + g * 8);
      acc[t] = __builtin_amdgcn_mfma_f32_16x16x32_bf16(af, bf, acc[t], 0, 0, 0);
    }
  }

  if (wid) {
    #pragma unroll
    for (int t = 0; t < 4; ++t)
      #pragma unroll
      for (int r = 0; r < 4; ++r) sred[wid - 1][lane][t * 4 + r] = acc[t][r];
  }
  __syncthreads();
  if (wid == 0) {
    float bias = b_ih[j] + b_hh[j];
    #pragma unroll
    for (int t = 0; t < 4; ++t)
      #pragma unroll
      for (int r = 0; r < 4; ++r) {
        float s = acc[t][r] + sred[0][lane][t * 4 + r] + sred[1][lane][t * 4 + r] +
                  sred[2][lane][t * 4 + r];
        int brow = t * 16 + g * 4 + r;
        gates[brow * H4 + j] = s + bias;
      }
  }
}

// ---------------- K3: LSTM cell elementwise (+ h1 bf16 copy) ----------------
__global__ __launch_bounds__(256) void k_lstm_cell(
    const float* __restrict__ gates, const float* __restrict__ c0,
    float* __restrict__ h1, float* __restrict__ c1, short* __restrict__ h1bf) {
  int idx = blockIdx.x * 256 + threadIdx.x;  // B*H
  int b = idx >> 9, h = idx & 511;
  const float* g = gates + b * H4;
  float gi = g[h], gf = g[H + h], gg = g[2 * H + h], go = g[3 * H + h];
  float c = sigf(gf) * c0[idx] + sigf(gi) * tanhf(gg);
  c1[idx] = c;
  float hv = sigf(go) * tanhf(c);
  h1[idx] = hv;
  h1bf[idx] = bf16c(hv);
}

// ---------------- K4: attn[b][m] = m_emb[mt[m][b]] . h1[b] ----------------
__global__ __launch_bounds__(256) void k_attn_scores(
    const float* __restrict__ m_emb, const int* __restrict__ mt,
    const float* __restrict__ h1, float* __restrict__ attn) {
  int wave = (blockIdx.x * 256 + threadIdx.x) >> 6;
  int lane = threadIdx.x & 63;
  int m = wave >> 6, b = wave & 63;
  int row = mt[m * B + b];
  const float4* e = (const float4*)(m_emb + (size_t)row * H);
  const float4* hv = (const float4*)(h1 + b * H);
  float4 a0 = e[lane], a1 = e[64 + lane];
  float4 b0 = hv[lane], b1 = hv[64 + lane];
  float acc = a0.x * b0.x + a0.y * b0.y + a0.z * b0.z + a0.w * b0.w +
              a1.x * b1.x + a1.y * b1.y + a1.z * b1.z + a1.w * b1.w;
  for (int off = 32; off > 0; off >>= 1) acc += __shfl_down(acc, off);
  if (lane == 0) attn[b * M + m] = acc;
}

// ---------------- K5: attn2 = attn @ attn_W^T + attn_b; log_softmax ----------------
__global__ __launch_bounds__(256) void k_attn_lin_lsm(
    const float* __restrict__ attn, const float* __restrict__ attn_W,
    const float* __restrict__ attn_b, float* __restrict__ attn_d) {
  __shared__ float arow[M];
  __shared__ float vals[256];
  __shared__ float red[256];
  int b = blockIdx.x, tid = threadIdx.x;
  if (tid < M) arow[tid] = attn[b * M + tid];
  __syncthreads();
  float v = -1e30f;
  if (tid < M) {
    const float* w = attn_W + tid * M;
    float a0 = attn_b[tid], a1 = 0.f;
    for (int m = 0; m < M; m += 2) {
      a0 = fmaf(arow[m], w[m], a0);
      a1 = fmaf(arow[m + 1], w[m + 1], a1);
    }
    v = a0 + a1;
  }
  vals[tid] = v;
  red[tid] = v;
  __syncthreads();
  for (int off = 128; off > 0; off >>= 1) {
    if (tid < off) red[tid] = fmaxf(red[tid], red[tid + off]);
    __syncthreads();
  }
  float mx = red[0];
  __syncthreads();
  red[tid] = (tid < M) ? expf(vals[tid] - mx) : 0.f;
  __syncthreads();
  for (int off = 128; off > 0; off >>= 1) {
    if (tid < off) red[tid] += red[tid + off];
    __syncthreads();
  }
  float lse = mx + logf(red[0]);
  if (tid < M) attn_d[b * M + tid] = vals[tid] - lse;
}

// ---------------- K6: memory_context partial sums over 4 m-chunks of 50 ----------------
__global__ __launch_bounds__(256) void k_mem_ctx_partial(
    const float* __restrict__ c_emb, const int* __restrict__ mt,
    const float* __restrict__ attn_d, float* __restrict__ mcp) {
  int b = blockIdx.x;     // 64
  int chunk = blockIdx.y; // 4
  int tid = threadIdx.x;  // 256
  __shared__ int rows[50];
  __shared__ float w[50];
  if (tid < 50) {
    int m = chunk * 50 + tid;
    rows[tid] = mt[m * B + b];
    w[tid] = attn_d[b * M + m];
  }
  __syncthreads();
  float acc0 = 0.f, acc1 = 0.f;
  #pragma unroll 5
  for (int i = 0; i < 50; ++i) {
    const float* e = c_emb + (size_t)rows[i] * H;
    acc0 = fmaf(w[i], e[tid], acc0);
    acc1 = fmaf(w[i], e[256 + tid], acc1);
  }
  mcp[(chunk * B + b) * H + tid] = acc0;
  mcp[(chunk * B + b) * H + 256 + tid] = acc1;
}

// K6b: reduce partials -> mc bf16
__global__ __launch_bounds__(256) void k_mem_ctx_reduce(
    const float* __restrict__ mcp, short* __restrict__ mcbf) {
  int idx = blockIdx.x * 256 + threadIdx.x;  // B*H
  float s = 0.f;
  for (int c = 0; c < 4; ++c) s += mcp[c * (B * H) + idx];
  mcbf[idx] = bf16c(s);
}

// ---------------- K7: GRU gates via MFMA. grid 192: half (gi/gh) x 96 col-tiles ----------------
__global__ __launch_bounds__(256) void k_gru_gates_mfma(
    const short* __restrict__ mcbf, const short* __restrict__ h1bf,
    const float* __restrict__ W_ih, const float* __restrict__ W_hh,
    const float* __restrict__ b_ih, const float* __restrict__ b_hh,
    float* __restrict__ gi, float* __restrict__ gh) {
  __shared__ float sred[3][64][16];
  const int tid = threadIdx.x;
  const int lane = tid & 63, wid = tid >> 6;
  const int col = lane & 15, g = lane >> 4;
  const int half = blockIdx.x / 96;
  const int j = (blockIdx.x % 96) * 16 + col;   // 0..1535
  const short* A = half ? h1bf : mcbf;
  const float* W = half ? W_hh : W_ih;
  const float* bias = half ? b_hh : b_ih;
  float* out = half ? gh : gi;
  const int kbase = wid * 128;

  f32x4 acc[4];
  #pragma unroll
  for (int t = 0; t < 4; ++t) acc[t] = (f32x4)(0.f);

  #pragma unroll
  for (int it = 0; it < 4; ++it) {
    int k0 = kbase + it * 32;
    const float* wp = W + (size_t)j * H + k0 + g * 8;
    float4 wa = *(const float4*)wp;
    float4 wb = *(const float4*)(wp + 4);
    short8 bf;
    bf[0] = bf16c(wa.x); bf[1] = bf16c(wa.y); bf[2] = bf16c(wa.z); bf[3] = bf16c(wa.w);
    bf[4] = bf16c(wb.x); bf[5] = bf16c(wb.y); bf[6] = bf16c(wb.z); bf[7] = bf16c(wb.w);
    #pragma unroll
    for (int t = 0; t < 4; ++t) {
      short8 af = *(const short8*)(A + (size_t)(col + t * 16) * H + k0 + g * 8);
      acc[t] = __builtin_amdgcn_mfma_f32_16x16x32_bf16(af, bf, acc[t], 0, 0, 0);
    }
  }

  if (wid) {
    #pragma unroll
    for (int t = 0; t < 4; ++t)
      #pragma unroll
      for (int r = 0; r < 4; ++r) sred[wid - 1][lane][t * 4 + r] = acc[t][r];
  }
  __syncthreads();
  if (wid == 0) {
    float bv = bias[j];
    #pragma unroll
    for (int t = 0; t < 4; ++t)
      #pragma unroll
      for (int r = 0; r < 4; ++r) {
        float s = acc[t][r] + sred[0][lane][t * 4 + r] + sred[1][lane][t * 4 + r] +
                  sred[2][lane][t * 4 + r];
        int brow = t * 16 + g * 4 + r;
        out[brow * H3 + j] = s + bv;
      }
  }
}

// ---------------- K8: GRU combine + build A (bf16) = [mb, ctx] ----------------
__global__ __launch_bounds__(256) void k_gru_combine(
    const float* __restrict__ gi, const float* __restrict__ gh,
    const float* __restrict__ h1, const float* __restrict__ ctx,
    short* __restrict__ Abf) {
  int idx = blockIdx.x * 256 + threadIdx.x;  // B*H
  int b = idx >> 9, h = idx & 511;
  const float* gib = gi + b * H3;
  const float* ghb = gh + b * H3;
  float r = sigf(gib[h] + ghb[h]);
  float z = sigf(gib[H + h] + ghb[H + h]);
  float n = tanhf(gib[2 * H + h] + r * ghb[2 * H + h]);
  float mb = (1.f - z) * n + z * h1[idx];
  Abf[b * H2 + h] = bf16c(mb);
  Abf[b * H2 + H + h] = bf16c(ctx[idx]);
}

// ---------------- K9: logits = A @ W^T + bias — LDS-staged double-buffered MFMA ----------------
// grid NB=786 blocks x 512 threads (8 waves). Per block: 64 vocab rows x 64 batch.
// LDS: W,A tiles bf16 [2 stages][64 rows][8 chunks of 8 elems], XOR-swizzled chunk^(row&7).
// Staging: contiguous 256B-per-row global loads (stream-friendly), cvt in reg, ds_write_b128.
// Wave w: col-tile ct=w&3 (16 vocab), batch-half bh=w>>2 (32 rows). Fused per-block LSE partials.
__global__ __launch_bounds__(512) void k_out_gemm_mfma(
    const short* __restrict__ Abf, const float* __restrict__ W,
    const float* __restrict__ bias, float* __restrict__ out,
    float* __restrict__ pm, float* __restrict__ ps) {
  __shared__ short8 Wl[1024];   // 2*64*8 chunks = 16 KB
  __shared__ short8 Al[1024];   // 16 KB
  __shared__ float spm[8][32];
  __shared__ float sps[8][32];
  const int tid = threadIdx.x;
  const int v0 = blockIdx.x * 64;

  // staging role: row sr (0..63), chunk sj (0..7); each thread: 32B W + 16B A per stage
  const int sr = tid >> 3, sj = tid & 7;
  const int sidx = sr * 8 + (sj ^ (sr & 7));
  int vr = v0 + sr; if (vr >= V) vr = V - 1;
  const float* wsrc = W + (size_t)vr * H2 + sj * 8;
  const short8* asrc = (const short8*)(Abf + sr * H2 + sj * 8);

  // compute role
  const int lane = tid & 63, wid = tid >> 6;
  const int col = lane & 15, g = lane >> 4;
  const int ct = wid & 3, bh = wid >> 2;
  const int wrow = ct * 16 + col;
  const int a0r = bh * 32 + col;
  const int a1r = a0r + 16;

  f32x4 acc0 = (f32x4)(0.f), acc1 = (f32x4)(0.f);

  // prologue: stage kt=0 into buf 0
  {
    float4 wa = *(const float4*)(wsrc);
    float4 wb = *(const float4*)(wsrc + 4);
    short8 av = asrc[0];
    short8 wv;
    wv[0] = bf16c(wa.x); wv[1] = bf16c(wa.y); wv[2] = bf16c(wa.z); wv[3] = bf16c(wa.w);
    wv[4] = bf16c(wb.x); wv[5] = bf16c(wb.y); wv[6] = bf16c(wb.z); wv[7] = bf16c(wb.w);
    Wl[sidx] = wv;
    Al[sidx] = av;
  }
  __syncthreads();

  int cur = 0;
  for (int kt = 0; kt < 16; ++kt) {
    // issue next-stage global loads early (hide HBM latency under MFMA)
    float4 nwa, nwb;
    short8 nav;
    if (kt < 15) {
      nwa = *(const float4*)(wsrc + (kt + 1) * 64);
      nwb = *(const float4*)(wsrc + (kt + 1) * 64 + 4);
      nav = asrc[(kt + 1) * 8];
    }
    // compute from buf[cur]
    const short8* Wb = Wl + cur * 512;
    const short8* Ab = Al + cur * 512;
    #pragma unroll
    for (int kw = 0; kw < 2; ++kw) {
      int c = kw * 4 + g;
      short8 bf  = Wb[wrow * 8 + (c ^ (wrow & 7))];
      short8 af0 = Ab[a0r * 8 + (c ^ (a0r & 7))];
      short8 af1 = Ab[a1r * 8 + (c ^ (a1r & 7))];
      acc0 = __builtin_amdgcn_mfma_f32_16x16x32_bf16(af0, bf, acc0, 0, 0, 0);
      acc1 = __builtin_amdgcn_mfma_f32_16x16x32_bf16(af1, bf, acc1, 0, 0, 0);
    }
    // write next stage to buf[cur^1] (disjoint from cur: no barrier needed before)
    if (kt < 15) {
      short8 wv;
      wv[0] = bf16c(nwa.x); wv[1] = bf16c(nwa.y); wv[2] = bf16c(nwa.z); wv[3] = bf16c(nwa.w);
      wv[4] = bf16c(nwb.x); wv[5] = bf16c(nwb.y); wv[6] = bf16c(nwb.z); wv[7] = bf16c(nwb.w);
      Wl[(cur ^ 1) * 512 + sidx] = wv;
      Al[(cur ^ 1) * 512 + sidx] = nav;
      __syncthreads();   // writes visible before next iter's reads
      cur ^= 1;
    }
  }

  // epilogue: store + fused per-block LSE partials
  const int v = v0 + ct * 16 + col;
  const float bv = (v < V) ? bias[v] : 0.f;
  #pragma unroll
  for (int ai = 0; ai < 2; ++ai) {
    f32x4 a = ai ? acc1 : acc0;
    #pragma unroll
    for (int r = 0; r < 4; ++r) {
      int b = bh * 32 + ai * 16 + g * 4 + r;
      float x = a[r] + bv;
      if (v < V) out[(size_t)b * V + v] = x;
      float xm = (v < V) ? x : -1e30f;
      float mx = xm;
      #pragma unroll
      for (int off = 1; off < 16; off <<= 1) mx = fmaxf(mx, __shfl_xor(mx, off));
      float e = (v < V) ? expf(xm - mx) : 0.f;
      #pragma unroll
      for (int off = 1; off < 16; off <<= 1) e += __shfl_xor(e, off);
      if (col == 0) {
        spm[wid][ai * 16 + g * 4 + r] = mx;
        sps[wid][ai * 16 + g * 4 + r] = e;
      }
    }
  }
  __syncthreads();
  if (tid < 64) {
    int b = tid;
    int wbase = (b >> 5) * 4;
    int bl = b & 31;
    float m = spm[wbase][bl], s = sps[wbase][bl];
    #pragma unroll
    for (int w = 1; w < 4; ++w) {
      float m2 = spm[wbase + w][bl], s2 = sps[wbase + w][bl];
      float nm = fmaxf(m, m2);
      s = s * expf(m - nm) + s2 * expf(m2 - nm);
      m = nm;
    }
    pm[(size_t)b * NB + blockIdx.x] = m;
    ps[(size_t)b * NB + blockIdx.x] = s;
  }
}

// ---------------- K10: combine partials -> lse[b] ----------------
__global__ __launch_bounds__(256) void k_lsm_finalize(
    const float* __restrict__ pm, const float* __restrict__ ps,
    float* __restrict__ lse) {
  int b = blockIdx.x, tid = threadIdx.x;
  float m = -1e30f, s = 0.f;
  for (int gq = tid; gq < NB; gq += 256) {
    float m2 = pm[(size_t)b * NB + gq], s2 = ps[(size_t)b * NB + gq];
    float nm = fmaxf(m, m2);
    s = s * expf(m - nm) + s2 * expf(m2 - nm);
    m = nm;
  }
  __shared__ float sm[256], ss[256];
  sm[tid] = m; ss[tid] = s;
  __syncthreads();
  for (int off = 128; off > 0; off >>= 1) {
    if (tid < off) {
      float m1 = sm[tid], s1 = ss[tid];
      float m2 = sm[tid + off], s2 = ss[tid + off];
      float nm = fmaxf(m1, m2);
      sm[tid] = nm;
      ss[tid] = s1 * expf(m1 - nm) + s2 * expf(m2 - nm);
    }
    __syncthreads();
  }
  if (tid == 0) lse[b] = sm[0] + logf(ss[0]);
}

// ---------------- K11: out -= lse[b]. grid (50, B) ----------------
__global__ __launch_bounds__(256) void k_lsm_apply(
    float* __restrict__ out, const float* __restrict__ lse) {
  int b = blockIdx.y, tid = threadIdx.x;
  float l = lse[b];
  int v = blockIdx.x * 1024 + tid * 4;
  float* row = out + (size_t)b * V;
  if (v + 3 < V) {
    float4 x = *(const float4*)(row + v);
    x.x -= l; x.y -= l; x.z -= l; x.w -= l;
    *(float4*)(row + v) = x;
  } else {
    for (int i = 0; i < 4 && v + i < V; ++i) row[v + i] -= l;
  }
}

extern "C" void kernel_launch(void* const* d_in, const int* in_sizes, int n_in,
                              void* d_out, int out_size, void* d_ws, size_t ws_size,
                              hipStream_t stream) {
  const float* h0    = (const float*)d_in[0];
  const float* c0    = (const float*)d_in[1];
  const float* ctx   = (const float*)d_in[2];
  const float* emb   = (const float*)d_in[3];
  const float* m_emb = (const float*)d_in[4];
  const float* c_emb = (const float*)d_in[5];
  const float* lWih  = (const float*)d_in[6];
  const float* lWhh  = (const float*)d_in[7];
  const float* lbih  = (const float*)d_in[8];
  const float* lbhh  = (const float*)d_in[9];
  const float* gWih  = (const float*)d_in[10];
  const float* gWhh  = (const float*)d_in[11];
  const float* gbih  = (const float*)d_in[12];
  const float* gbhh  = (const float*)d_in[13];
  const float* aW    = (const float*)d_in[14];
  const float* ab    = (const float*)d_in[15];
  const float* oW    = (const float*)d_in[16];
  const float* ob    = (const float*)d_in[17];
  const int* ids     = (const int*)d_in[18];
  const int* mt      = (const int*)d_in[19];

  float* out = (float*)d_out;
  float* h1  = out + (size_t)B * V;
  float* c1  = h1 + B * H;

  // Workspace layout — offsets in FLOAT units; bf16 buffers counted as shorts/2 floats.
  float* ws    = (float*)d_ws;
  short* Albf  = (short*)ws;                   // 64*1536 shorts = 49152 fl
  float* gates = ws + 49152;                   // B*H4 = 131072 fl
  short* h1bf  = (short*)(gates + B * H4);     // 64*512 shorts = 16384 fl
  float* attn  = gates + B * H4 + 16384;       // B*M = 12800 fl
  float* attnd = attn + B * M;                 // 12800 fl
  float* mcp   = attnd + B * M;                // 4*B*H = 131072 fl
  short* mcbf  = (short*)(mcp + 4 * B * H);    // 64*512 shorts = 16384 fl
  float* gi    = mcp + 4 * B * H + 16384;      // B*H3 = 98304 fl
  float* gh    = gi + B * H3;                  // 98304 fl
  short* Abf   = (short*)(gh + B * H3);        // 64*1024 shorts = 32768 fl
  float* pm    = gh + B * H3 + 32768;          // B*NB = 50304 fl
  float* ps    = pm + (size_t)B * NB;          // 50304 fl
  float* lse   = ps + (size_t)B * NB;          // 64 fl

  dim3 g1(6, B);
  k_build_A<<<g1, 256, 0, stream>>>(emb, ctx, h0, ids, Albf);
  k_lstm_gates_mfma<<<128, 256, 0, stream>>>(Albf, lWih, lWhh, lbih, lbhh, gates);
  k_lstm_cell<<<(B * H) / 256, 256, 0, stream>>>(gates, c0, h1, c1, h1bf);
  k_attn_scores<<<(M * B) / 4, 256, 0, stream>>>(m_emb, mt, h1, attn);
  k_attn_lin_lsm<<<B, 256, 0, stream>>>(attn, aW, ab, attnd);
  dim3 g6(B, 4);
  k_mem_ctx_partial<<<g6, 256, 0, stream>>>(c_emb, mt, attnd, mcp);
  k_mem_ctx_reduce<<<(B * H) / 256, 256, 0, stream>>>(mcp, mcbf);
  k_gru_gates_mfma<<<192, 256, 0, stream>>>(mcbf, h1bf, gWih, gWhh, gbih, gbhh, gi, gh);
  k_gru_combine<<<(B * H) / 256, 256, 0, stream>>>(gi, gh, h1, ctx, Abf);
  k_out_gemm_mfma<<<NB, 512, 0, stream>>>(Abf, oW, ob, out, pm, ps);
  k_lsm_finalize<<<B, 256, 0, stream>>>(pm, ps, lse);
  dim3 g11(50, B);
  k_lsm_apply<<<g11, 256, 0, stream>>>(out, lse);
}

// Round 7
// 109.634 us; speedup vs baseline: 3.8198x; 1.0101x over previous
//
#include <hip/hip_runtime.h>
#include <math.h>

#define B 64
#define H 512
#define V 50257
#define M 200
#define H2 1024
#define H3 1536
#define H4 2048
#define NB 786             // ceil(V/64) = out-GEMM blocks

typedef short short8 __attribute__((ext_vector_type(8)));
typedef float f32x4 __attribute__((ext_vector_type(4)));

__device__ __forceinline__ float sigf(float x) { return 1.f / (1.f + expf(-x)); }

// f32 -> bf16 (RNE) as raw short
__device__ __forceinline__ short bf16c(float f) {
  unsigned u = __builtin_bit_cast(unsigned, f);
  unsigned r = u + 0x7fffu + ((u >> 16) & 1u);
  return (short)(r >> 16);
}

__device__ __forceinline__ short8 cvt8(float4 a, float4 b) {
  short8 w;
  w[0] = bf16c(a.x); w[1] = bf16c(a.y); w[2] = bf16c(a.z); w[3] = bf16c(a.w);
  w[4] = bf16c(b.x); w[5] = bf16c(b.y); w[6] = bf16c(b.z); w[7] = bf16c(b.w);
  return w;
}

// ---------------- K1: A_lstm[b][k] = [relu(emb[ids[b]]) | ctx[b] | h0[b]] (bf16) ----------------
__global__ __launch_bounds__(256) void k_build_A(
    const float* __restrict__ emb, const float* __restrict__ ctx,
    const float* __restrict__ h0, const int* __restrict__ ids,
    short* __restrict__ A) {
  int k = blockIdx.x * 256 + threadIdx.x;   // 0..1535
  int b = blockIdx.y;
  float v;
  if (k < 512) {
    v = emb[(size_t)ids[b] * H + k];
    v = v > 0.f ? v : 0.f;
  } else if (k < 1024) {
    v = ctx[b * H + (k - 512)];
  } else {
    v = h0[b * H + (k - 1024)];
  }
  A[b * H3 + k] = bf16c(v);
}

// ---------------- K2: LSTM gates via MFMA. grid 128 (16 j-cols each), 4 waves k-split ----------------
__global__ __launch_bounds__(256) void k_lstm_gates_mfma(
    const short* __restrict__ A, const float* __restrict__ W_ih,
    const float* __restrict__ W_hh, const float* __restrict__ b_ih,
    const float* __restrict__ b_hh, float* __restrict__ gates) {
  __shared__ float sred[3][64][16];
  const int tid = threadIdx.x;
  const int lane = tid & 63, wid = tid >> 6;
  const int col = lane & 15, g = lane >> 4;
  const int j = blockIdx.x * 16 + col;      // gate-row 0..2047
  const int kbase = wid * 384;

  f32x4 acc[4];
  #pragma unroll
  for (int t = 0; t < 4; ++t) acc[t] = (f32x4)(0.f);

  #pragma unroll 2
  for (int it = 0; it < 12; ++it) {
    int k0 = kbase + it * 32;
    const float* wp;
    if (k0 < 1024) wp = W_ih + (size_t)j * H2 + k0 + g * 8;
    else           wp = W_hh + (size_t)j * H + (k0 - 1024) + g * 8;
    float4 wa = *(const float4*)wp;
    float4 wb = *(const float4*)(wp + 4);
    short8 bf = cvt8(wa, wb);
    #pragma unroll
    for (int t = 0; t < 4; ++t) {
      short8 af = *(const short8*)(A + (size_t)(col + t * 16) * H3 + k0 + g * 8);
      acc[t] = __builtin_amdgcn_mfma_f32_16x16x32_bf16(af, bf, acc[t], 0, 0, 0);
    }
  }

  if (wid) {
    #pragma unroll
    for (int t = 0; t < 4; ++t)
      #pragma unroll
      for (int r = 0; r < 4; ++r) sred[wid - 1][lane][t * 4 + r] = acc[t][r];
  }
  __syncthreads();
  if (wid == 0) {
    float bias = b_ih[j] + b_hh[j];
    #pragma unroll
    for (int t = 0; t < 4; ++t)
      #pragma unroll
      for (int r = 0; r < 4; ++r) {
        float s = acc[t][r] + sred[0][lane][t * 4 + r] + sred[1][lane][t * 4 + r] +
                  sred[2][lane][t * 4 + r];
        int brow = t * 16 + g * 4 + r;
        gates[brow * H4 + j] = s + bias;
      }
  }
}

// ---------------- K3: LSTM cell elementwise (+ h1 bf16 copy) ----------------
__global__ __launch_bounds__(256) void k_lstm_cell(
    const float* __restrict__ gates, const float* __restrict__ c0,
    float* __restrict__ h1, float* __restrict__ c1, short* __restrict__ h1bf) {
  int idx = blockIdx.x * 256 + threadIdx.x;  // B*H
  int b = idx >> 9, h = idx & 511;
  const float* g = gates + b * H4;
  float gi = g[h], gf = g[H + h], gg = g[2 * H + h], go = g[3 * H + h];
  float c = sigf(gf) * c0[idx] + sigf(gi) * tanhf(gg);
  c1[idx] = c;
  float hv = sigf(go) * tanhf(c);
  h1[idx] = hv;
  h1bf[idx] = bf16c(hv);
}

// ---------------- K4: attn[b][m] = m_emb[mt[m][b]] . h1[b] ----------------
__global__ __launch_bounds__(256) void k_attn_scores(
    const float* __restrict__ m_emb, const int* __restrict__ mt,
    const float* __restrict__ h1, float* __restrict__ attn) {
  int wave = (blockIdx.x * 256 + threadIdx.x) >> 6;
  int lane = threadIdx.x & 63;
  int m = wave >> 6, b = wave & 63;
  int row = mt[m * B + b];
  const float4* e = (const float4*)(m_emb + (size_t)row * H);
  const float4* hv = (const float4*)(h1 + b * H);
  float4 a0 = e[lane], a1 = e[64 + lane];
  float4 b0 = hv[lane], b1 = hv[64 + lane];
  float acc = a0.x * b0.x + a0.y * b0.y + a0.z * b0.z + a0.w * b0.w +
              a1.x * b1.x + a1.y * b1.y + a1.z * b1.z + a1.w * b1.w;
  for (int off = 32; off > 0; off >>= 1) acc += __shfl_down(acc, off);
  if (lane == 0) attn[b * M + m] = acc;
}

// ---------------- K5: attn2 = attn @ attn_W^T + attn_b; log_softmax ----------------
__global__ __launch_bounds__(256) void k_attn_lin_lsm(
    const float* __restrict__ attn, const float* __restrict__ attn_W,
    const float* __restrict__ attn_b, float* __restrict__ attn_d) {
  __shared__ float arow[M];
  __shared__ float vals[256];
  __shared__ float red[256];
  int b = blockIdx.x, tid = threadIdx.x;
  if (tid < M) arow[tid] = attn[b * M + tid];
  __syncthreads();
  float v = -1e30f;
  if (tid < M) {
    const float* w = attn_W + tid * M;
    float a0 = attn_b[tid], a1 = 0.f;
    for (int m = 0; m < M; m += 2) {
      a0 = fmaf(arow[m], w[m], a0);
      a1 = fmaf(arow[m + 1], w[m + 1], a1);
    }
    v = a0 + a1;
  }
  vals[tid] = v;
  red[tid] = v;
  __syncthreads();
  for (int off = 128; off > 0; off >>= 1) {
    if (tid < off) red[tid] = fmaxf(red[tid], red[tid + off]);
    __syncthreads();
  }
  float mx = red[0];
  __syncthreads();
  red[tid] = (tid < M) ? expf(vals[tid] - mx) : 0.f;
  __syncthreads();
  for (int off = 128; off > 0; off >>= 1) {
    if (tid < off) red[tid] += red[tid + off];
    __syncthreads();
  }
  float lse = mx + logf(red[0]);
  if (tid < M) attn_d[b * M + tid] = vals[tid] - lse;
}

// ---------------- K6: memory_context partial sums over 4 m-chunks of 50 ----------------
__global__ __launch_bounds__(256) void k_mem_ctx_partial(
    const float* __restrict__ c_emb, const int* __restrict__ mt,
    const float* __restrict__ attn_d, float* __restrict__ mcp) {
  int b = blockIdx.x;     // 64
  int chunk = blockIdx.y; // 4
  int tid = threadIdx.x;  // 256
  __shared__ int rows[50];
  __shared__ float w[50];
  if (tid < 50) {
    int m = chunk * 50 + tid;
    rows[tid] = mt[m * B + b];
    w[tid] = attn_d[b * M + m];
  }
  __syncthreads();
  float acc0 = 0.f, acc1 = 0.f;
  #pragma unroll 5
  for (int i = 0; i < 50; ++i) {
    const float* e = c_emb + (size_t)rows[i] * H;
    acc0 = fmaf(w[i], e[tid], acc0);
    acc1 = fmaf(w[i], e[256 + tid], acc1);
  }
  mcp[(chunk * B + b) * H + tid] = acc0;
  mcp[(chunk * B + b) * H + 256 + tid] = acc1;
}

// K6b: reduce partials -> mc bf16
__global__ __launch_bounds__(256) void k_mem_ctx_reduce(
    const float* __restrict__ mcp, short* __restrict__ mcbf) {
  int idx = blockIdx.x * 256 + threadIdx.x;  // B*H
  float s = 0.f;
  for (int c = 0; c < 4; ++c) s += mcp[c * (B * H) + idx];
  mcbf[idx] = bf16c(s);
}

// ---------------- K7: GRU gates via MFMA. grid 192: half (gi/gh) x 96 col-tiles ----------------
__global__ __launch_bounds__(256) void k_gru_gates_mfma(
    const short* __restrict__ mcbf, const short* __restrict__ h1bf,
    const float* __restrict__ W_ih, const float* __restrict__ W_hh,
    const float* __restrict__ b_ih, const float* __restrict__ b_hh,
    float* __restrict__ gi, float* __restrict__ gh) {
  __shared__ float sred[3][64][16];
  const int tid = threadIdx.x;
  const int lane = tid & 63, wid = tid >> 6;
  const int col = lane & 15, g = lane >> 4;
  const int half = blockIdx.x / 96;
  const int j = (blockIdx.x % 96) * 16 + col;   // 0..1535
  const short* A = half ? h1bf : mcbf;
  const float* W = half ? W_hh : W_ih;
  const float* bias = half ? b_hh : b_ih;
  float* out = half ? gh : gi;
  const int kbase = wid * 128;

  f32x4 acc[4];
  #pragma unroll
  for (int t = 0; t < 4; ++t) acc[t] = (f32x4)(0.f);

  #pragma unroll
  for (int it = 0; it < 4; ++it) {
    int k0 = kbase + it * 32;
    const float* wp = W + (size_t)j * H + k0 + g * 8;
    float4 wa = *(const float4*)wp;
    float4 wb = *(const float4*)(wp + 4);
    short8 bf = cvt8(wa, wb);
    #pragma unroll
    for (int t = 0; t < 4; ++t) {
      short8 af = *(const short8*)(A + (size_t)(col + t * 16) * H + k0 + g * 8);
      acc[t] = __builtin_amdgcn_mfma_f32_16x16x32_bf16(af, bf, acc[t], 0, 0, 0);
    }
  }

  if (wid) {
    #pragma unroll
    for (int t = 0; t < 4; ++t)
      #pragma unroll
      for (int r = 0; r < 4; ++r) sred[wid - 1][lane][t * 4 + r] = acc[t][r];
  }
  __syncthreads();
  if (wid == 0) {
    float bv = bias[j];
    #pragma unroll
    for (int t = 0; t < 4; ++t)
      #pragma unroll
      for (int r = 0; r < 4; ++r) {
        float s = acc[t][r] + sred[0][lane][t * 4 + r] + sred[1][lane][t * 4 + r] +
                  sred[2][lane][t * 4 + r];
        int brow = t * 16 + g * 4 + r;
        out[brow * H3 + j] = s + bv;
      }
  }
}

// ---------------- K8: GRU combine + build A (bf16) = [mb, ctx] ----------------
__global__ __launch_bounds__(256) void k_gru_combine(
    const float* __restrict__ gi, const float* __restrict__ gh,
    const float* __restrict__ h1, const float* __restrict__ ctx,
    short* __restrict__ Abf) {
  int idx = blockIdx.x * 256 + threadIdx.x;  // B*H
  int b = idx >> 9, h = idx & 511;
  const float* gib = gi + b * H3;
  const float* ghb = gh + b * H3;
  float r = sigf(gib[h] + ghb[h]);
  float z = sigf(gib[H + h] + ghb[H + h]);
  float n = tanhf(gib[2 * H + h] + r * ghb[2 * H + h]);
  float mb = (1.f - z) * n + z * h1[idx];
  Abf[b * H2 + h] = bf16c(mb);
  Abf[b * H2 + H + h] = bf16c(ctx[idx]);
}

// ---------------- K9: logits = A @ W^T + bias — LDS-staged, DEPTH-3 pipelined MFMA ----------------
// grid NB=786 x 512 threads (8 waves). Per block: 64 vocab rows x 64 batch, BK=64, 16 K-steps.
// Pipeline (T14 issue-early/write-late): at iter kt issue global loads for stage kt+2,
// compute stage kt from LDS[cur], then ds_write stage kt+1 (issued a full iter ago) to LDS[cur^1].
// Two static register stage-sets (a/b) — parity fully unrolled so indices are compile-time.
__global__ __launch_bounds__(512) void k_out_gemm_mfma(
    const short* __restrict__ Abf, const float* __restrict__ W,
    const float* __restrict__ bias, float* __restrict__ out,
    float* __restrict__ pm, float* __restrict__ ps) {
  __shared__ short8 Wl[1024];   // 2 stages * 64 rows * 8 chunks = 16 KB
  __shared__ short8 Al[1024];   // 16 KB
  __shared__ float spm[8][32];
  __shared__ float sps[8][32];
  const int tid = threadIdx.x;
  const int v0 = blockIdx.x * 64;

  // staging role: row sr (0..63), chunk sj (0..7); 32B W + 16B A per stage per thread
  const int sr = tid >> 3, sj = tid & 7;
  const int sidx = sr * 8 + (sj ^ (sr & 7));
  int vr = v0 + sr; if (vr >= V) vr = V - 1;
  const float* wsrc = W + (size_t)vr * H2 + sj * 8;
  const short8* asrc = (const short8*)(Abf + sr * H2 + sj * 8);

  // compute role
  const int lane = tid & 63, wid = tid >> 6;
  const int col = lane & 15, g = lane >> 4;
  const int ct = wid & 3, bh = wid >> 2;
  const int wrow = ct * 16 + col;
  const int a0r = bh * 32 + col;
  const int a1r = a0r + 16;

  f32x4 acc0 = (f32x4)(0.f), acc1 = (f32x4)(0.f);

  float4 wa_a, wb_a, wa_b, wb_b;
  short8 av_a, av_b;

  // prologue: issue stage 0 (set a) and stage 1 (set b); write stage 0
  wa_a = *(const float4*)(wsrc);
  wb_a = *(const float4*)(wsrc + 4);
  av_a = asrc[0];
  wa_b = *(const float4*)(wsrc + 64);
  wb_b = *(const float4*)(wsrc + 68);
  av_b = asrc[8];
  Wl[sidx] = cvt8(wa_a, wb_a);
  Al[sidx] = av_a;
  __syncthreads();

  int cur = 0;
  #pragma unroll
  for (int kp = 0; kp < 8; ++kp) {
    // ---- even iter kt0 = 2kp: LDS[cur]=stage kt0; regs_b = stage kt0+1 (in flight) ----
    if (2 * kp + 2 < 16) {   // issue stage kt0+2 -> set a
      wa_a = *(const float4*)(wsrc + (2 * kp + 2) * 64);
      wb_a = *(const float4*)(wsrc + (2 * kp + 2) * 64 + 4);
      av_a = asrc[(2 * kp + 2) * 8];
    }
    {
      const short8* Wb = Wl + cur * 512;
      const short8* Ab = Al + cur * 512;
      #pragma unroll
      for (int kw = 0; kw < 2; ++kw) {
        int c = kw * 4 + g;
        short8 bf  = Wb[wrow * 8 + (c ^ (wrow & 7))];
        short8 af0 = Ab[a0r * 8 + (c ^ (a0r & 7))];
        short8 af1 = Ab[a1r * 8 + (c ^ (a1r & 7))];
        acc0 = __builtin_amdgcn_mfma_f32_16x16x32_bf16(af0, bf, acc0, 0, 0, 0);
        acc1 = __builtin_amdgcn_mfma_f32_16x16x32_bf16(af1, bf, acc1, 0, 0, 0);
      }
    }
    // write stage kt0+1 (set b) -> LDS[cur^1]   (always: kt0+1 = 2kp+1 <= 15)
    Wl[(cur ^ 1) * 512 + sidx] = cvt8(wa_b, wb_b);
    Al[(cur ^ 1) * 512 + sidx] = av_b;
    __syncthreads();
    cur ^= 1;

    // ---- odd iter kt1 = 2kp+1: regs_a = stage kt1+1 (in flight) ----
    if (2 * kp + 3 < 16) {   // issue stage kt1+2 -> set b
      wa_b = *(const float4*)(wsrc + (2 * kp + 3) * 64);
      wb_b = *(const float4*)(wsrc + (2 * kp + 3) * 64 + 4);
      av_b = asrc[(2 * kp + 3) * 8];
    }
    {
      const short8* Wb = Wl + cur * 512;
      const short8* Ab = Al + cur * 512;
      #pragma unroll
      for (int kw = 0; kw < 2; ++kw) {
        int c = kw * 4 + g;
        short8 bf  = Wb[wrow * 8 + (c ^ (wrow & 7))];
        short8 af0 = Ab[a0r * 8 + (c ^ (a0r & 7))];
        short8 af1 = Ab[a1r * 8 + (c ^ (a1r & 7))];
        acc0 = __builtin_amdgcn_mfma_f32_16x16x32_bf16(af0, bf, acc0, 0, 0, 0);
        acc1 = __builtin_amdgcn_mfma_f32_16x16x32_bf16(af1, bf, acc1, 0, 0, 0);
      }
    }
    if (2 * kp + 2 < 16) {   // write stage kt1+1 (set a); skip at kp=7 (stage 16)
      Wl[(cur ^ 1) * 512 + sidx] = cvt8(wa_a, wb_a);
      Al[(cur ^ 1) * 512 + sidx] = av_a;
      __syncthreads();
      cur ^= 1;
    }
  }

  // epilogue: store + fused per-block LSE partials
  const int v = v0 + ct * 16 + col;
  const float bv = (v < V) ? bias[v] : 0.f;
  #pragma unroll
  for (int ai = 0; ai < 2; ++ai) {
    f32x4 a = ai ? acc1 : acc0;
    #pragma unroll
    for (int r = 0; r < 4; ++r) {
      int b = bh * 32 + ai * 16 + g * 4 + r;
      float x = a[r] + bv;
      if (v < V) out[(size_t)b * V + v] = x;
      float xm = (v < V) ? x : -1e30f;
      float mx = xm;
      #pragma unroll
      for (int off = 1; off < 16; off <<= 1) mx = fmaxf(mx, __shfl_xor(mx, off));
      float e = (v < V) ? expf(xm - mx) : 0.f;
      #pragma unroll
      for (int off = 1; off < 16; off <<= 1) e += __shfl_xor(e, off);
      if (col == 0) {
        spm[wid][ai * 16 + g * 4 + r] = mx;
        sps[wid][ai * 16 + g * 4 + r] = e;
      }
    }
  }
  __syncthreads();
  if (tid < 64) {
    int b = tid;
    int wbase = (b >> 5) * 4;
    int bl = b & 31;
    float m = spm[wbase][bl], s = sps[wbase][bl];
    #pragma unroll
    for (int w = 1; w < 4; ++w) {
      float m2 = spm[wbase + w][bl], s2 = sps[wbase + w][bl];
      float nm = fmaxf(m, m2);
      s = s * expf(m - nm) + s2 * expf(m2 - nm);
      m = nm;
    }
    pm[(size_t)b * NB + blockIdx.x] = m;
    ps[(size_t)b * NB + blockIdx.x] = s;
  }
}

// ---------------- K10: combine partials -> lse[b] ----------------
__global__ __launch_bounds__(256) void k_lsm_finalize(
    const float* __restrict__ pm, const float* __restrict__ ps,
    float* __restrict__ lse) {
  int b = blockIdx.x, tid = threadIdx.x;
  float m = -1e30f, s = 0.f;
  for (int gq = tid; gq < NB; gq += 256) {
    float m2 = pm[(size_t)b * NB + gq], s2 = ps[(size_t)b * NB + gq];
    float nm = fmaxf(m, m2);
    s = s * expf(m - nm) + s2 * expf(m2 - nm);
    m = nm;
  }
  __shared__ float sm[256], ss[256];
  sm[tid] = m; ss[tid] = s;
  __syncthreads();
  for (int off = 128; off > 0; off >>= 1) {
    if (tid < off) {
      float m1 = sm[tid], s1 = ss[tid];
      float m2 = sm[tid + off], s2 = ss[tid + off];
      float nm = fmaxf(m1, m2);
      sm[tid] = nm;
      ss[tid] = s1 * expf(m1 - nm) + s2 * expf(m2 - nm);
    }
    __syncthreads();
  }
  if (tid == 0) lse[b] = sm[0] + logf(ss[0]);
}

// ---------------- K11: out -= lse[b]. grid (50, B) ----------------
__global__ __launch_bounds__(256) void k_lsm_apply(
    float* __restrict__ out, const float* __restrict__ lse) {
  int b = blockIdx.y, tid = threadIdx.x;
  float l = lse[b];
  int v = blockIdx.x * 1024 + tid * 4;
  float* row = out + (size_t)b * V;
  if (v + 3 < V) {
    float4 x = *(const float4*)(row + v);
    x.x -= l; x.y -= l; x.z -= l; x.w -= l;
    *(float4*)(row + v) = x;
  } else {
    for (int i = 0; i < 4 && v + i < V; ++i) row[v + i] -= l;
  }
}

extern "C" void kernel_launch(void* const* d_in, const int* in_sizes, int n_in,
                              void* d_out, int out_size, void* d_ws, size_t ws_size,
                              hipStream_t stream) {
  const float* h0    = (const float*)d_in[0];
  const float* c0    = (const float*)d_in[1];
  const float* ctx   = (const float*)d_in[2];
  const float* emb   = (const float*)d_in[3];
  const float* m_emb = (const float*)d_in[4];
  const float* c_emb = (const float*)d_in[5];
  const float* lWih  = (const float*)d_in[6];
  const float* lWhh  = (const float*)d_in[7];
  const float* lbih  = (const float*)d_in[8];
  const float* lbhh  = (const float*)d_in[9];
  const float* gWih  = (const float*)d_in[10];
  const float* gWhh  = (const float*)d_in[11];
  const float* gbih  = (const float*)d_in[12];
  const float* gbhh  = (const float*)d_in[13];
  const float* aW    = (const float*)d_in[14];
  const float* ab    = (const float*)d_in[15];
  const float* oW    = (const float*)d_in[16];
  const float* ob    = (const float*)d_in[17];
  const int* ids     = (const int*)d_in[18];
  const int* mt      = (const int*)d_in[19];

  float* out = (float*)d_out;
  float* h1  = out + (size_t)B * V;
  float* c1  = h1 + B * H;

  // Workspace layout — offsets in FLOAT units; bf16 buffers counted as shorts/2 floats.
  float* ws    = (float*)d_ws;
  short* Albf  = (short*)ws;                   // 64*1536 shorts = 49152 fl
  float* gates = ws + 49152;                   // B*H4 = 131072 fl
  short* h1bf  = (short*)(gates + B * H4);     // 64*512 shorts = 16384 fl
  float* attn  = gates + B * H4 + 16384;       // B*M = 12800 fl
  float* attnd = attn + B * M;                 // 12800 fl
  float* mcp   = attnd + B * M;                // 4*B*H = 131072 fl
  short* mcbf  = (short*)(mcp + 4 * B * H);    // 64*512 shorts = 16384 fl
  float* gi    = mcp + 4 * B * H + 16384;      // B*H3 = 98304 fl
  float* gh    = gi + B * H3;                  // 98304 fl
  short* Abf   = (short*)(gh + B * H3);        // 64*1024 shorts = 32768 fl
  float* pm    = gh + B * H3 + 32768;          // B*NB = 50304 fl
  float* ps    = pm + (size_t)B * NB;          // 50304 fl
  float* lse   = ps + (size_t)B * NB;          // 64 fl

  dim3 g1(6, B);
  k_build_A<<<g1, 256, 0, stream>>>(emb, ctx, h0, ids, Albf);
  k_lstm_gates_mfma<<<128, 256, 0, stream>>>(Albf, lWih, lWhh, lbih, lbhh, gates);
  k_lstm_cell<<<(B * H) / 256, 256, 0, stream>>>(gates, c0, h1, c1, h1bf);
  k_attn_scores<<<(M * B) / 4, 256, 0, stream>>>(m_emb, mt, h1, attn);
  k_attn_lin_lsm<<<B, 256, 0, stream>>>(attn, aW, ab, attnd);
  dim3 g6(B, 4);
  k_mem_ctx_partial<<<g6, 256, 0, stream>>>(c_emb, mt, attnd, mcp);
  k_mem_ctx_reduce<<<(B * H) / 256, 256, 0, stream>>>(mcp, mcbf);
  k_gru_gates_mfma<<<192, 256, 0, stream>>>(mcbf, h1bf, gWih, gWhh, gbih, gbhh, gi, gh);
  k_gru_combine<<<(B * H) / 256, 256, 0, stream>>>(gi, gh, h1, ctx, Abf);
  k_out_gemm_mfma<<<NB, 512, 0, stream>>>(Abf, oW, ob, out, pm, ps);
  k_lsm_finalize<<<B, 256, 0, stream>>>(pm, ps, lse);
  dim3 g11(50, B);
  k_lsm_apply<<<g11, 256, 0, stream>>>(out, lse);
}